// Round 8
// baseline (1241.981 us; speedup 1.0000x reference)
//
#include <hip/hip_runtime.h>
#include <hip/hip_bf16.h>
#include <math.h>

#define BATCH 128
#define NNODE 400
#define HID   128
#define NN    (NNODE*NNODE)      // 160000
#define KSEL  32000              // int(NN*0.2)
#define EQCAP 1024
#define EPSF  1e-9f
#define TSPLIT 8
#define SEG   (NN / TSPLIT)      // 20000
#define NT    7                  // ceil(400/64)
#define KC400 14                 // 448/32
#define FRAGS (KC400*4096)       // shorts per plane, K=400pad, N=128
#define PLA   57344              // shorts per plane: 4 kchunks * 28 ntiles * 512 (dec1_w: K=128, N=448pad)

// map float -> unsigned so that descending float order == descending unsigned order
__device__ __forceinline__ unsigned tokey(float f) {
  unsigned u = __float_as_uint(f);
  return (u & 0x80000000u) ? ~u : (u | 0x80000000u);
}

// fp32 -> bf16 (RNE) and back, as raw shorts
__device__ __forceinline__ short f2bf(float f) {
  unsigned u = __float_as_uint(f);
  u += 0x7fffu + ((u >> 16) & 1u);
  return (short)(u >> 16);
}
__device__ __forceinline__ float bf2f(short s) {
  return __uint_as_float(((unsigned)(unsigned short)s) << 16);
}

// fisher transform via hw log2: 0.5*ln((1+x+e)/(1-x+e))/dnm == (log2(a)-log2(b))*cmul
// cmul = 0.5*ln2/dnm.  v_log_f32 is ~1ulp -> xf perturbation ~1e-9 abs (safe).
__device__ __forceinline__ float xfhw(float xv, float cmul) {
  float la = __builtin_amdgcn_logf(1.0f + xv + EPSF);
  float lb = __builtin_amdgcn_logf(1.0f - xv + EPSF);
  return (la - lb) * cmul;
}

typedef __attribute__((ext_vector_type(8))) short s8v;
typedef __attribute__((ext_vector_type(4))) short s4v;
typedef __attribute__((ext_vector_type(4))) float f4v;

// ---------------------------------------------------------------------------
// 64x64-tile fp32 GEMM (VALU) — only G3 (residual, in-place) still uses this.
// ---------------------------------------------------------------------------
#define BK 16
#define LP 68

template<bool AT, bool BIAS, bool RES, bool RELU, bool TS>
__global__ void __launch_bounds__(256) gemm64(
    const float* __restrict__ A, long sA, int lda,
    const float* __restrict__ B, long sB, int ldb,
    const float* __restrict__ bias,
    const float* __restrict__ Res, long sRes,
    float* __restrict__ C, long sC, int ldc,
    int M, int Nc, int K)
{
  __shared__ float As[BK][LP];
  __shared__ float Bs[BK][LP];
  const int bz = blockIdx.z;
  A += (size_t)bz * sA;
  B += (size_t)bz * sB;
  C += (size_t)bz * sC;
  const float* Rp = RES ? (Res + (size_t)bz * sRes) : nullptr;

  const int n0 = blockIdx.x * 64;
  const int m0 = blockIdx.y * 64;
  const int tid = threadIdx.x;
  const int tx = tid & 15, ty = tid >> 4;
  const bool edgeM = (m0 + 64 > M);
  const bool edgeN = (n0 + 64 > Nc);

  float acc[4][4];
#pragma unroll
  for (int i = 0; i < 4; ++i)
#pragma unroll
    for (int j = 0; j < 4; ++j) acc[i][j] = 0.f;

  for (int k0 = 0; k0 < K; k0 += BK) {
    if (!AT) {
      const int m = tid & 63, g = tid >> 6;
      if (!edgeM) {
        const float4 v = *(const float4*)(A + (size_t)(m0 + m) * lda + k0 + 4 * g);
        As[4 * g + 0][m] = v.x; As[4 * g + 1][m] = v.y;
        As[4 * g + 2][m] = v.z; As[4 * g + 3][m] = v.w;
      } else {
        const int gm = m0 + m;
        const bool ok = gm < M;
#pragma unroll
        for (int j = 0; j < 4; ++j)
          As[4 * g + j][m] = ok ? A[(size_t)gm * lda + k0 + 4 * g + j] : 0.f;
      }
    } else {
      const int k = tid >> 4, mg = tid & 15;
      if (!edgeM) {
        const float4 v = *(const float4*)(A + (size_t)(k0 + k) * lda + m0 + 4 * mg);
        *(float4*)&As[k][4 * mg] = v;
      } else {
#pragma unroll
        for (int j = 0; j < 4; ++j) {
          const int gm = m0 + 4 * mg + j;
          As[k][4 * mg + j] = (gm < M) ? A[(size_t)(k0 + k) * lda + gm] : 0.f;
        }
      }
    }
    {
      const int k = tid >> 4, ng = tid & 15;
      if (!edgeN) {
        const float4 v = *(const float4*)(B + (size_t)(k0 + k) * ldb + n0 + 4 * ng);
        *(float4*)&Bs[k][4 * ng] = v;
      } else {
#pragma unroll
        for (int j = 0; j < 4; ++j) {
          const int gn = n0 + 4 * ng + j;
          Bs[k][4 * ng + j] = (gn < Nc) ? B[(size_t)(k0 + k) * ldb + gn] : 0.f;
        }
      }
    }
    __syncthreads();
#pragma unroll
    for (int kk = 0; kk < BK; ++kk) {
      const float4 a = *(const float4*)&As[kk][ty << 2];
      const float4 b = *(const float4*)&Bs[kk][tx << 2];
      const float av[4] = {a.x, a.y, a.z, a.w};
      const float bv[4] = {b.x, b.y, b.z, b.w};
#pragma unroll
      for (int i = 0; i < 4; ++i)
#pragma unroll
        for (int j = 0; j < 4; ++j) acc[i][j] += av[i] * bv[j];
    }
    __syncthreads();
  }

#pragma unroll
  for (int i = 0; i < 4; ++i) {
    const int m = m0 + (ty << 2) + i;
    if (m >= M) continue;
#pragma unroll
    for (int j = 0; j < 4; ++j) {
      const int n = n0 + (tx << 2) + j;
      if (n >= Nc) continue;
      float v = acc[i][j];
      if (BIAS) v += bias[n];
      const size_t loc = TS ? ((size_t)n * ldc + m) : ((size_t)m * ldc + n);
      if (RES) v += Rp[loc];
      if (RELU) v = fmaxf(v, 0.f);
      C[loc] = v;
    }
  }
}

// ---------------------------------------------------------------------------
// bsplit5: all 5 weight-fragment builds in ONE launch (blockIdx.y selects).
// W[K][N] fp32 -> MFMA B-fragment bf16 hi/lo planes (Kpad x Npad).
// ---------------------------------------------------------------------------
__global__ void bsplit5(
    const float* __restrict__ gcn1_w, const float* __restrict__ gcn2_w,
    const float* __restrict__ enc1_w, const float* __restrict__ enc2_w,
    const float* __restrict__ dec1_w,
    short* __restrict__ w1frag, short* __restrict__ w2frag,
    short* __restrict__ e1frag, short* __restrict__ e2frag,
    short* __restrict__ dfrag) {
  const float* W; short* out; int K, Kpad, N, Npad;
  switch (blockIdx.y) {
    case 0: W = gcn1_w; out = w1frag; K = NNODE; Kpad = 448; N = HID;   Npad = 128; break;
    case 1: W = gcn2_w; out = w2frag; K = HID;   Kpad = 128; N = HID;   Npad = 128; break;
    case 2: W = enc1_w; out = e1frag; K = NNODE; Kpad = 448; N = HID;   Npad = 128; break;
    case 3: W = enc2_w; out = e2frag; K = NNODE; Kpad = 448; N = HID;   Npad = 128; break;
    default: W = dec1_w; out = dfrag; K = HID;   Kpad = 128; N = NNODE; Npad = 448; break;
  }
  int t = blockIdx.x * 256 + threadIdx.x;
  if (t >= Kpad * Npad) return;
  int k = t / Npad, n = t - k * Npad;
  float v = (k < K && n < N) ? W[(size_t)k * N + n] : 0.f;
  short hi = f2bf(v);
  short lo = f2bf(v - bf2f(hi));
  int ntiles = Npad >> 4;
  size_t idx = (((size_t)(k >> 5) * ntiles + (n >> 4)) * 64
                + (((k >> 3) & 3) * 16 + (n & 15))) * 8 + (k & 7);
  size_t PL = (size_t)(Kpad >> 5) * ntiles * 512;
  out[idx] = hi;
  out[PL + idx] = lo;
}

// ---------------------------------------------------------------------------
// MFMA GEMM (bf16 split-3), N fixed 128.
// C[m,n] = act( [scl[m]*] sum_k A[m,k]*B[k,n] + bias[n] )
// AT: A[m][k]=Araw[k*lda+m].  FRAG: emit frag-ordered bf16 hi/lo (next B).
// TS: store transposed C^T[n][m] via LDS.
// XF (only with !AT): A is raw x; apply fisher transform (hw log2, folded
// 1/dnm) during staging and ALSO write the result to xfout (fuses xf_k into G1).
// ---------------------------------------------------------------------------
template<bool AT, bool FRAG, bool BIAS, bool RELU, bool SCL, bool TS, bool XF>
__global__ void __launch_bounds__(256) mfgemm(
    const float* __restrict__ A, long sA, int lda,
    const short* __restrict__ Bf, long sB, int kc,
    const float* __restrict__ bias,
    const float* __restrict__ scl,
    float* __restrict__ Cf, long sCf, int ldc,
    short* __restrict__ Cfrag, long sCfrag, int okc,
    const float* __restrict__ denomp, float* __restrict__ xfout,
    int M, int K)
{
  __shared__ float As[64][68];
  const int bz = blockIdx.y;
  A += (size_t)bz * sA;
  Bf += (size_t)bz * sB;
  if (SCL) scl += (size_t)bz * NNODE;
  if (!FRAG) Cf += (size_t)bz * sCf;
  else       Cfrag += (size_t)bz * sCfrag;
  if (XF) xfout += (size_t)bz * sA;
  // 0.5*ln2 / dnm (one scalar divide per thread, hoisted out of the loop)
  const float cmul = XF ? (0.34657359027997264f / denomp[bz]) : 0.f;

  const int tid = threadIdx.x;
  const int lane = tid & 63, wave = tid >> 6;
  const int wqm = wave >> 1, wqn = wave & 1;
  const int quad = lane >> 4, l15 = lane & 15;
  const int m0 = blockIdx.x * 64;

  f4v acc[2][4];
#pragma unroll
  for (int i = 0; i < 2; ++i)
#pragma unroll
    for (int j = 0; j < 4; ++j) acc[i][j] = (f4v){0.f, 0.f, 0.f, 0.f};

  const int nstage = (K + 63) >> 6;
  for (int st = 0; st < nstage; ++st) {
    const int k0 = st << 6;
    if (st) __syncthreads();
    if (!AT) {
      const int mrow = tid >> 4;
      const int k4 = (tid & 15) << 2;
#pragma unroll
      for (int u = 0; u < 4; ++u) {
        const int m = mrow + (u << 4);
        const int gm = m0 + m, gk = k0 + k4;
        float4 v = {0.f, 0.f, 0.f, 0.f};
        if (gm < M) {
          if (gk + 4 <= K) {
            float4 xv = *(const float4*)(A + (size_t)gm * lda + gk);
            if (XF) {
              v.x = xfhw(xv.x, cmul);
              v.y = xfhw(xv.y, cmul);
              v.z = xfhw(xv.z, cmul);
              v.w = xfhw(xv.w, cmul);
              *(float4*)(xfout + (size_t)gm * lda + gk) = v;
            } else v = xv;
          } else {
            float* pv = (float*)&v;
#pragma unroll
            for (int j = 0; j < 4; ++j)
              if (gk + j < K) {
                float xv = A[(size_t)gm * lda + gk + j];
                if (XF) {
                  pv[j] = xfhw(xv, cmul);
                  xfout[(size_t)gm * lda + gk + j] = pv[j];
                } else pv[j] = xv;
              }
          }
        }
        *(float4*)&As[m][k4] = v;
      }
    } else {
      const int kk = tid >> 4;
      const int m4 = (tid & 15) << 2;
#pragma unroll
      for (int u = 0; u < 4; ++u) {
        const int gk = k0 + kk + (u << 4);
        float4 v = {0.f, 0.f, 0.f, 0.f};
        if (gk < K) {
          if (m0 + m4 + 4 <= M) v = *(const float4*)(A + (size_t)gk * lda + m0 + m4);
          else {
            float* pv = (float*)&v;
#pragma unroll
            for (int j = 0; j < 4; ++j)
              if (m0 + m4 + j < M) pv[j] = A[(size_t)gk * lda + m0 + m4 + j];
          }
        }
        As[m4 + 0][kk + (u << 4)] = v.x;
        As[m4 + 1][kk + (u << 4)] = v.y;
        As[m4 + 2][kk + (u << 4)] = v.z;
        As[m4 + 3][kk + (u << 4)] = v.w;
      }
    }
    __syncthreads();

#pragma unroll
    for (int c2 = 0; c2 < 2; ++c2) {
      const int c = (st << 1) + c2;
      s8v bhi[4], blo[4];
#pragma unroll
      for (int nt = 0; nt < 4; ++nt) {
        const int ntg = (wqn << 2) + nt;
        const size_t off = (((size_t)c * 8 + ntg) * 64 + lane) * 8;
        bhi[nt] = *(const s8v*)(Bf + off);
        blo[nt] = *(const s8v*)(Bf + (size_t)kc * 4096 + off);
      }
#pragma unroll
      for (int mt = 0; mt < 2; ++mt) {
        const int row = (wqm << 5) + (mt << 4) + l15;
        const int kof = (c2 << 5) + (quad << 3);
        const f4v a0 = *(const f4v*)&As[row][kof];
        const f4v a1 = *(const f4v*)&As[row][kof + 4];
        s8v ah, al;
#pragma unroll
        for (int j = 0; j < 4; ++j) {
          short h0 = f2bf(a0[j]); ah[j] = h0; al[j] = f2bf(a0[j] - bf2f(h0));
          short h1 = f2bf(a1[j]); ah[j + 4] = h1; al[j + 4] = f2bf(a1[j] - bf2f(h1));
        }
#pragma unroll
        for (int nt = 0; nt < 4; ++nt) {
          acc[mt][nt] = __builtin_amdgcn_mfma_f32_16x16x32_bf16(ah, bhi[nt], acc[mt][nt], 0, 0, 0);
          acc[mt][nt] = __builtin_amdgcn_mfma_f32_16x16x32_bf16(ah, blo[nt], acc[mt][nt], 0, 0, 0);
          acc[mt][nt] = __builtin_amdgcn_mfma_f32_16x16x32_bf16(al, bhi[nt], acc[mt][nt], 0, 0, 0);
        }
      }
    }
  }

  // ---- epilogue ----
  if (TS) {
    for (int nh = 0; nh < 2; ++nh) {
      __syncthreads();
      if (wqn == nh) {
#pragma unroll
        for (int mt = 0; mt < 2; ++mt)
#pragma unroll
          for (int nt = 0; nt < 4; ++nt) {
            const int tn = (nt << 4) + l15;
            const int n  = (wqn << 6) + tn;
            const int mc = (wqm << 5) + (mt << 4) + (quad << 2);
            const f4v a = acc[mt][nt];
#pragma unroll
            for (int reg = 0; reg < 4; ++reg) {
              float v = a[reg];
              if (SCL) v *= scl[m0 + mc + reg];
              if (BIAS) v += bias[n];
              if (RELU) v = fmaxf(v, 0.f);
              As[tn][mc + reg] = v;
            }
          }
      }
      __syncthreads();
      const int row = tid >> 2, cq = tid & 3;
#pragma unroll
      for (int u = 0; u < 4; ++u) {
        const int col = (cq + (u << 2)) << 2;
        if (m0 + col + 4 <= M) {
          const float4 v = *(const float4*)&As[row][col];
          *(float4*)(Cf + (size_t)((nh << 6) + row) * ldc + m0 + col) = v;
        }
      }
    }
    return;
  }

#pragma unroll
  for (int mt = 0; mt < 2; ++mt) {
    const int mb = m0 + (wqm << 5) + (mt << 4) + (quad << 2);
#pragma unroll
    for (int nt = 0; nt < 4; ++nt) {
      const int n = (wqn << 6) + (nt << 4) + l15;
      const f4v a = acc[mt][nt];
      if (!FRAG) {
#pragma unroll
        for (int reg = 0; reg < 4; ++reg) {
          const int m = mb + reg;
          if (m < M) {
            float v = a[reg];
            if (SCL) v *= scl[m];
            if (BIAS) v += bias[n];
            if (RELU) v = fmaxf(v, 0.f);
            Cf[(size_t)m * ldc + n] = v;
          }
        }
      } else {
        s4v h4, l4;
#pragma unroll
        for (int reg = 0; reg < 4; ++reg) {
          const int m = mb + reg;
          float v = (m < M) ? (SCL ? a[reg] * scl[m] : a[reg]) : 0.f;
          short hh = f2bf(v);
          h4[reg] = hh; l4[reg] = f2bf(v - bf2f(hh));
        }
        const int chunkT = mb >> 5, quadT = (mb >> 3) & 3, jT0 = mb & 7;
        const size_t off = (((size_t)chunkT * 8 + (wqn << 2) + nt) * 64
                            + quadT * 16 + l15) * 8 + jT0;
        *(s4v*)(Cfrag + off) = h4;
        *(s4v*)(Cfrag + (size_t)okc * 4096 + off) = l4;
      }
    }
  }
}

// ---------------------------------------------------------------------------
// g4mf v7: proven-best structure (R6/R7, ~86 µs): d1-only epilogue, strided
// o1 A-loads, packed 2x-u16 12-bit LDS histogram (bits 31..20).
// ---------------------------------------------------------------------------
__global__ void __launch_bounds__(256) g4mf(
    const float* __restrict__ o1,    // [B][128][400] fp32 (out2b)
    const short* __restrict__ wfrag, // dec1_w frags, 2 planes of PLA
    const float* __restrict__ bias,  // dec1_b
    float* __restrict__ xf,          // in-place -> x2
    unsigned* __restrict__ ghist)    // [B][4096]
{
  __shared__ float D2[64][68];       // 17408 B
  __shared__ unsigned hist[2048];    // 4096 bins packed as 2x u16, 8192 B
  const int b = blockIdx.y;
  int p = blockIdx.x, bi = 0;
  while (p >= NT - bi) { p -= NT - bi; ++bi; }
  const int bj = bi + p;
  const int I0 = bi * 64, J0 = bj * 64;
  const bool diag = (bi == bj);

  o1 += (size_t)b * HID * NNODE;
  xf += (size_t)b * NN;
  unsigned* gh = ghist + (size_t)b * 4096;

  const int tid = threadIdx.x;
  const int lane = tid & 63, wave = tid >> 6;
  const int wq = wave & 1;
  const bool d1 = wave < 2;
  const int Bt = (d1 ? bj : bi) * 4;   // B ntile base (global, in wfrag)
  const int quad = lane >> 4, l15 = lane & 15;
  const int M0 = d1 ? I0 : J0;

  for (int i = tid; i < 2048; i += 256) hist[i] = 0u;

  f4v acc[2][4];
#pragma unroll
  for (int i = 0; i < 2; ++i)
#pragma unroll
    for (int j = 0; j < 4; ++j) acc[i][j] = (f4v){0.f, 0.f, 0.f, 0.f};

  const int gm0 = M0 + (wq << 5) + l15;    // mt=0 output row; mt=1 is +16

  for (int c = 0; c < 4; ++c) {
    const int k0 = c << 5;
    // ---- B frags from global (pre-split, frag-ordered) ----
    s8v bhi[4], blo[4];
#pragma unroll
    for (int nt = 0; nt < 4; ++nt) {
      const int ntg = Bt + nt;
      const size_t off = (((size_t)c * 28 + ntg) * 64 + lane) * 8;
      bhi[nt] = *(const s8v*)(wfrag + off);
      blo[nt] = *(const s8v*)(wfrag + PLA + off);
    }
    // ---- A frags straight from o1 columns (split in registers) ----
#pragma unroll
    for (int mt = 0; mt < 2; ++mt) {
      const int gm = gm0 + (mt << 4);
      float av[8];
      if (gm < NNODE) {
        const float* cp = o1 + (size_t)(k0 + (quad << 3)) * NNODE + gm;
#pragma unroll
        for (int j = 0; j < 8; ++j) av[j] = cp[(size_t)j * NNODE];
      } else {
#pragma unroll
        for (int j = 0; j < 8; ++j) av[j] = 0.f;
      }
      s8v ah, al;
#pragma unroll
      for (int j = 0; j < 8; ++j) {
        short h = f2bf(av[j]); ah[j] = h; al[j] = f2bf(av[j] - bf2f(h));
      }
#pragma unroll
      for (int nt = 0; nt < 4; ++nt) {
        acc[mt][nt] = __builtin_amdgcn_mfma_f32_16x16x32_bf16(ah, bhi[nt], acc[mt][nt], 0, 0, 0);
        acc[mt][nt] = __builtin_amdgcn_mfma_f32_16x16x32_bf16(ah, blo[nt], acc[mt][nt], 0, 0, 0);
        acc[mt][nt] = __builtin_amdgcn_mfma_f32_16x16x32_bf16(al, bhi[nt], acc[mt][nt], 0, 0, 0);
      }
    }
  }

  // waves 2/3: dump delta2[m'][n'] to LDS
  if (!d1) {
#pragma unroll
    for (int mt = 0; mt < 2; ++mt) {
      const int mb = (wq << 5) + (mt << 4) + (quad << 2);
#pragma unroll
      for (int nt = 0; nt < 4; ++nt) {
        const int nn = (nt << 4) + l15;
        const f4v a = acc[mt][nt];
#pragma unroll
        for (int reg = 0; reg < 4; ++reg) D2[mb + reg][nn] = a[reg];
      }
    }
  }
  __syncthreads();

  // waves 0/1: form x2 tile (I,J), write both (I,J) and (J,I), histogram
  if (d1) {
    const unsigned w = diag ? 1u : 2u;
#pragma unroll
    for (int mt = 0; mt < 2; ++mt) {
      const int a0 = (wq << 5) + (mt << 4) + (quad << 2);
#pragma unroll
      for (int nt = 0; nt < 4; ++nt) {
        const int nn = (nt << 4) + l15;
        const int gj = J0 + nn;
        const f4v d1v = acc[mt][nt];
        const f4v d2t = *(const f4v*)&D2[nn][a0];
        f4v vv;
#pragma unroll
        for (int reg = 0; reg < 4; ++reg) {
          const int gi = I0 + a0 + reg;
          float v = 0.f;
          if (gi < NNODE && gj < NNODE) {
            v = xf[(size_t)gi * NNODE + gj];
            if (gi != gj)
              v += 0.5f * (d1v[reg] + d2t[reg] + bias[gj] + bias[gi]);
            const unsigned bin = tokey(v) >> 20;
            atomicAdd(&hist[bin >> 1], w << ((bin & 1) << 4));
          }
          vv[reg] = v;
        }
#pragma unroll
        for (int reg = 0; reg < 4; ++reg) {
          const int gi = I0 + a0 + reg;
          if (gi < NNODE && gj < NNODE) xf[(size_t)gi * NNODE + gj] = vv[reg];
        }
        if (!diag && gj < NNODE && (I0 + a0 + 4 <= NNODE)) {
          *(float4*)(xf + (size_t)gj * NNODE + I0 + a0) = *(float4*)&vv;
        }
      }
    }
  }
  __syncthreads();
  for (int i = tid; i < 2048; i += 256) {
    const unsigned v = hist[i];
    const unsigned lo = v & 0xFFFFu, hi = v >> 16;
    if (lo) atomicAdd(&gh[2 * i], lo);
    if (hi) atomicAdd(&gh[2 * i + 1], hi);
  }
}

// ---------------------------------------------------------------------------
// tzd: fused init (ghist 4096-bin zero, per-sample state, deg zero) + denom.
// ---------------------------------------------------------------------------
__global__ void tzd(const float* __restrict__ x, unsigned* __restrict__ ghist,
                    unsigned* __restrict__ sprefix, int* __restrict__ sk,
                    int* __restrict__ eqcnt, float* __restrict__ deg,
                    float* __restrict__ denom, unsigned* __restrict__ ccnt) {
  int t = blockIdx.x * 256 + threadIdx.x;
  if (t < BATCH * 4096) ghist[t] = 0u;
  if (t < BATCH) {
    sprefix[t] = 0u; sk[t] = KSEL; eqcnt[t] = 0; ccnt[t] = 0u;
    float v = x[(size_t)t * NN];
    denom[t] = 0.5f * logf((1.0f + v + EPSF) / (1.0f - v + EPSF));
  }
  if (t < BATCH * NNODE) deg[t] = 0.f;
}

// ---------------------------------------------------------------------------
// thistA: pass A of radix select — bins = bits 19..8 (4096), prefix = top 12.
// ALSO compacts every matching KEY into cand[b*NN + *] (wave-aggregated
// append: 1 global atomic per wave per quad-element, ballot+popcount for
// in-wave offsets). List order is arbitrary; histogram counts downstream are
// order-independent, so selection is unchanged.
// ---------------------------------------------------------------------------
__global__ void __launch_bounds__(256) thistA(const float* __restrict__ x2,
                                              const unsigned* __restrict__ sprefix,
                                              unsigned* __restrict__ ghist,
                                              unsigned* __restrict__ cand,
                                              unsigned* __restrict__ ccnt) {
  __shared__ unsigned h[4096];
  const int b  = blockIdx.y;
  const int sb = blockIdx.x;
  const int tid = threadIdx.x;
  const int lane = tid & 63;
  for (int i = tid; i < 4096; i += 256) h[i] = 0u;
  __syncthreads();

  const unsigned prefix = sprefix[b];
  unsigned* cb = cand + (size_t)b * NN;
  const float4* p4 = (const float4*)(x2 + (size_t)b * NN);
  const int i0 = sb * (SEG / 4), i1 = i0 + (SEG / 4);
  for (int i = i0 + tid; i < i1; i += 256) {
    float4 v = p4[i];
    unsigned kk[4] = {tokey(v.x), tokey(v.y), tokey(v.z), tokey(v.w)};
#pragma unroll
    for (int q = 0; q < 4; ++q) {
      const unsigned key = kk[q];
      const bool m = (key & 0xFFF00000u) == prefix;
      if (m) atomicAdd(&h[(key >> 8) & 4095u], 1u);
      const unsigned long long bal = __ballot(m);
      if (bal) {
        unsigned base = 0;
        if (lane == 0) base = atomicAdd(&ccnt[b], (unsigned)__popcll(bal));
        base = __shfl(base, 0);
        if (m) cb[base + __popcll(bal & ((1ull << lane) - 1ull))] = key;
      }
    }
  }
  __syncthreads();
  for (int i = tid; i < 4096; i += 256) {
    unsigned s = h[i];
    if (s) atomicAdd(&ghist[(size_t)b * 4096 + i], s);
  }
}

// ---------------------------------------------------------------------------
// tpick12<SH>: select the 12-bit bin from a 4096-bin histogram (two-level
// scan: 256 chunk sums, then <=16-bin walk). Updates sprefix/sk; zeroes ghist.
// ---------------------------------------------------------------------------
template<int SH>
__global__ void __launch_bounds__(256) tpick12(unsigned* __restrict__ ghist,
                                               unsigned* __restrict__ sprefix,
                                               int* __restrict__ sk) {
  const int b = blockIdx.x;
  __shared__ unsigned h[4096];
  __shared__ unsigned csum[256];
  unsigned* gh = ghist + (size_t)b * 4096;
  unsigned local = 0;
#pragma unroll
  for (int u = 0; u < 16; ++u) {
    unsigned v = gh[threadIdx.x * 16 + u];
    h[threadIdx.x * 16 + u] = v;
    local += v;
  }
  csum[threadIdx.x] = local;
  __syncthreads();
  if (threadIdx.x == 0) {
    int k = sk[b];
    int bin = 0;
    for (int ch = 255; ch >= 0; --ch) {
      int S = (int)csum[ch];
      if (S >= k) {
        for (int bb = ch * 16 + 15; bb >= ch * 16; --bb) {
          int c = (int)h[bb];
          if (c >= k) { bin = bb; break; }
          k -= c;
        }
        break;
      }
      k -= S;
    }
    sprefix[b] = sprefix[b] | ((unsigned)bin << SH);
    sk[b] = k;
  }
#pragma unroll
  for (int u = 0; u < 16; ++u) gh[threadIdx.x * 16 + u] = 0u;
}

// ---------------------------------------------------------------------------
// thistC: final 8-bit pass over the COMPACT candidate list (keys matching
// the pass-0 12-bit prefix, gathered by thistA) instead of re-scanning all
// 82 MB. One block per sample; filters on the 24-bit prefix, builds the
// 256-bin histogram in LDS, and picks tau/rrem directly (fuses old tpick8f).
// ---------------------------------------------------------------------------
__global__ void __launch_bounds__(256) thistC(const unsigned* __restrict__ cand,
                                              const unsigned* __restrict__ ccnt,
                                              const unsigned* __restrict__ sprefix,
                                              const int* __restrict__ sk,
                                              unsigned* __restrict__ tau,
                                              int* __restrict__ rrem) {
  __shared__ unsigned h[8][256];
  const int b = blockIdx.x;
  const int tid = threadIdx.x;
  for (int i = tid; i < 8 * 256; i += 256) ((unsigned*)h)[i] = 0u;
  __syncthreads();
  const unsigned prefix = sprefix[b];           // top 24 bits set
  const unsigned n = ccnt[b];
  const unsigned* cp = cand + (size_t)b * NN;
  const int rep = tid & 7;
  for (unsigned i = tid; i < n; i += 256) {
    const unsigned key = cp[i];
    if ((key & 0xFFFFFF00u) == prefix) atomicAdd(&h[rep][key & 255u], 1u);
  }
  __syncthreads();
  if (tid < 256) {
    const unsigned s = h[0][tid] + h[1][tid] + h[2][tid] + h[3][tid]
                     + h[4][tid] + h[5][tid] + h[6][tid] + h[7][tid];
    h[0][tid] = s;
  }
  __syncthreads();
  if (tid == 0) {
    int k = sk[b];
    unsigned byte = 0u;
    for (int bin = 255; bin >= 0; --bin) {
      int c = (int)h[0][bin];
      if (c >= k) { byte = (unsigned)bin; break; }
      k -= c;
    }
    tau[b] = prefix | byte;
    rrem[b] = k;
  }
}

// ---------------------------------------------------------------------------
// build_kc: A = x2 masked (key > tau), tie gathering, AND per-column sums
// (fuses old deg_k). Block = (16-row group, sample). deg zeroed in tzd.
// ---------------------------------------------------------------------------
__global__ void __launch_bounds__(256) build_kc(
    const float* __restrict__ x2, const unsigned* __restrict__ tau,
    float* __restrict__ A, float* __restrict__ deg,
    int* __restrict__ eqcnt, int* __restrict__ eqidx) {
  __shared__ float cs[NNODE];
  const int b = blockIdx.y, rg = blockIdx.x;
  const int tid = threadIdx.x;
  for (int i = tid; i < NNODE; i += 256) cs[i] = 0.f;
  __syncthreads();
  const unsigned tk = tau[b];
  const size_t base = (size_t)b * NN + (size_t)rg * 6400;
  for (int u = 0; u < 25; ++u) {
    const int t = u * 256 + tid;          // < 6400 = 16 rows * 400 cols
    const float v = x2[base + t];
    const unsigned key = tokey(v);
    const float a = (key > tk) ? v : 0.f;
    A[base + t] = a;
    if (key == tk) {
      int p = atomicAdd(&eqcnt[b], 1);
      if (p < EQCAP) eqidx[b * EQCAP + p] = rg * 6400 + t;
    }
    if (a != 0.f) atomicAdd(&cs[t % NNODE], a);
  }
  __syncthreads();
  for (int j = tid; j < NNODE; j += 256)
    if (cs[j] != 0.f) atomicAdd(&deg[b * NNODE + j], cs[j]);
}

// ---------------------------------------------------------------------------
// eqdinv: fused tie-fix + diag-fill + dinv, one block per sample.
// ---------------------------------------------------------------------------
__global__ void __launch_bounds__(256) eqdinv(
    float* __restrict__ A, const float* __restrict__ x2,
    float* __restrict__ deg, float* __restrict__ dinv,
    const int* __restrict__ eqcnt, const int* __restrict__ eqidx,
    const int* __restrict__ rrem) {
  const int b = blockIdx.x;
  int cnt = eqcnt[b]; if (cnt > EQCAP) cnt = EQCAP;
  const int r = rrem[b];
  for (int t = threadIdx.x; t < cnt; t += 256) {
    int idx = eqidx[b * EQCAP + t];
    int rank = 0;
    for (int u = 0; u < cnt; ++u) rank += (eqidx[b * EQCAP + u] < idx) ? 1 : 0;
    if (rank < r) {
      float v = x2[(size_t)b * NN + idx];
      A[(size_t)b * NN + idx] = v;
      atomicAdd(&deg[b * NNODE + idx % NNODE], v);
    }
  }
  __syncthreads();
  for (int j = threadIdx.x; j < NNODE; j += 256) {
    float d = deg[b * NNODE + j];
    size_t o = (size_t)b * NN + (size_t)j * NNODE + j;
    if (A[o] == 0.f) { A[o] = 1.0f; d += 1.0f; }
    dinv[b * NNODE + j] = (d == 0.f) ? 0.f : 1.0f / sqrtf(d);
  }
}

__global__ void head_k(const float* __restrict__ h2, const float* __restrict__ fc_w,
                       const float* __restrict__ fc_b, float* __restrict__ out) {
  int b = blockIdx.x;
  int f = threadIdx.x;
  float s = 0.f;
  const float* p = h2 + (size_t)b * NNODE * HID + f;
  for (int j = 0; j < NNODE; ++j) s += p[(size_t)j * HID];
  float pv = fmaxf(s / (float)NNODE, 0.f);
  __shared__ float r0[128], r1[128];
  r0[f] = pv * fc_w[f * 2 + 0];
  r1[f] = pv * fc_w[f * 2 + 1];
  __syncthreads();
  for (int sft = 64; sft > 0; sft >>= 1) {
    if (f < sft) { r0[f] += r0[f + sft]; r1[f] += r1[f + sft]; }
    __syncthreads();
  }
  if (f == 0) {
    out[b * 2 + 0] = r0[0] + fc_b[0];
    out[b * 2 + 1] = r1[0] + fc_b[1];
  }
}

// ---------------------------------------------------------------------------
extern "C" void kernel_launch(void* const* d_in, const int* in_sizes, int n_in,
                              void* d_out, int out_size, void* d_ws, size_t ws_size,
                              hipStream_t stream) {
  const float* x      = (const float*)d_in[0];
  const float* enc1_w = (const float*)d_in[2];
  const float* enc1_b = (const float*)d_in[3];
  const float* enc2_w = (const float*)d_in[4];
  const float* enc2_b = (const float*)d_in[5];
  const float* dec2_w = (const float*)d_in[6];
  const float* dec2_b = (const float*)d_in[7];
  const float* dec1_w = (const float*)d_in[8];
  const float* dec1_b = (const float*)d_in[9];
  const float* gcn1_w = (const float*)d_in[10];
  const float* gcn1_b = (const float*)d_in[11];
  const float* gcn2_w = (const float*)d_in[12];
  const float* gcn2_b = (const float*)d_in[13];
  const float* fc_w   = (const float*)d_in[14];
  const float* fc_b   = (const float*)d_in[15];
  float* out = (float*)d_out;
  (void)in_sizes; (void)n_in; (void)out_size; (void)ws_size;

  float* ws = (float*)d_ws;
  size_t off = 0;
  auto take = [&](size_t n) { float* p = ws + off; off += (n + 63) & ~(size_t)63; return p; };
  float* xf   = take((size_t)BATCH * NN);          // xf -> x2 (in place)
  float* dl   = take((size_t)BATCH * NN);          // cand keys (radix), then A (sparsified)
  float* o1   = take((size_t)BATCH * HID * NNODE); // out1 -> out2b; later xwfrag alias
  float* o2   = take((size_t)BATCH * HID * HID);
  float* hbuf = take((size_t)BATCH * NNODE * HID); // h -> h2
  float* denom = take(BATCH);
  float* dinv  = take((size_t)BATCH * NNODE);
  float* deg   = take((size_t)BATCH * NNODE);
  unsigned* tau = (unsigned*)take(BATCH);
  int* rrem  = (int*)take(BATCH);
  int* eqcnt = (int*)take(BATCH);
  int* eqidx = (int*)take((size_t)BATCH * EQCAP);
  unsigned* ghist   = (unsigned*)take((size_t)BATCH * 4096);   // 12-bit bins
  unsigned* sprefix = (unsigned*)take(BATCH);
  int*      sk      = (int*)take(BATCH);
  unsigned* ccnt    = (unsigned*)take(BATCH);
  short* w1frag = (short*)take((size_t)FRAGS + 64);          // gcn1_w, 2 planes K448
  short* w2frag = (short*)take((size_t)4 * 4096 + 64);       // gcn2_w, 2 planes K128
  short* e1frag = (short*)take((size_t)FRAGS + 64);          // enc1_w
  short* e2frag = (short*)take((size_t)FRAGS + 64);          // enc2_w
  short* dfrag  = (short*)take((size_t)PLA + 64);            // dec1_w (2*PLA shorts)
  short* xwfrag = (short*)o1;          // aliases dead o1 (post-g4mf)
  unsigned* cand = (unsigned*)dl;      // candidate keys, dead before build_kc
  const long sXW = 2L * FRAGS;

  tzd<<<2048, 256, 0, stream>>>(x, ghist, sprefix, sk, eqcnt, deg, denom, ccnt);
  bsplit5<<<dim3(224, 5), 256, 0, stream>>>(gcn1_w, gcn2_w, enc1_w, enc2_w, dec1_w,
                                            w1frag, w2frag, e1frag, e2frag, dfrag);

  // G1 (+fused xf): reads raw x, computes/stores xf, o1 = (relu(xf@enc1_w+b))^T
  mfgemm<false, false, true, true, false, true, true><<<dim3(7, BATCH), 256, 0, stream>>>(
      x, NN, NNODE, e1frag, 0, KC400, enc1_b, nullptr,
      o1, (long)HID * NNODE, NNODE, nullptr, 0, 0, denom, xf, NNODE, NNODE);
  // G2: o2 = relu(o1 @ enc2_w + b)
  mfgemm<false, false, true, true, false, false, false><<<dim3(2, BATCH), 256, 0, stream>>>(
      o1, (long)HID * NNODE, NNODE, e2frag, 0, KC400, enc2_b, nullptr,
      o2, (long)HID * HID, HID, nullptr, 0, 0, nullptr, nullptr, HID, NNODE);
  // G3: out2b = relu(o2 @ dec2_w + b + o1), in-place (fp32)
  gemm64<false, true, true, true, false><<<dim3(7, 2, BATCH), 256, 0, stream>>>(
      o2, (long)HID * HID, HID, dec2_w, 0, NNODE, dec2_b,
      o1, (long)HID * NNODE, o1, (long)HID * NNODE, NNODE, HID, NNODE, HID);

  // fused delta + symmetrize + x2 + pass-0 12-bit histogram (packed LDS)
  g4mf<<<dim3(NT * (NT + 1) / 2, BATCH), 256, 0, stream>>>(o1, dfrag, dec1_b, xf, ghist);

  // radix select: 12 + 12 + 8 bits; pass B runs on the compact candidate list
  tpick12<20><<<BATCH, 256, 0, stream>>>(ghist, sprefix, sk);
  thistA<<<dim3(TSPLIT, BATCH), 256, 0, stream>>>(xf, sprefix, ghist, cand, ccnt);
  tpick12<8><<<BATCH, 256, 0, stream>>>(ghist, sprefix, sk);
  thistC<<<BATCH, 256, 0, stream>>>(cand, ccnt, sprefix, sk, tau, rrem);

  // A build + column sums (fused deg), then fused tie-fix + diag-fill + dinv
  build_kc<<<dim3(25, BATCH), 256, 0, stream>>>(xf, tau, dl, deg, eqcnt, eqidx);
  eqdinv<<<BATCH, 256, 0, stream>>>(dl, xf, deg, dinv, eqcnt, eqidx, rrem);

  // ---- post-top-k GCN: MFMA bf16 split-3 ----
  mfgemm<false, true, false, false, true, false, false><<<dim3(7, BATCH), 256, 0, stream>>>(
      xf, NN, NNODE, w1frag, 0, KC400, nullptr, dinv,
      nullptr, 0, 128, xwfrag, sXW, KC400, nullptr, nullptr, NNODE, NNODE);
  mfgemm<true, false, true, true, true, false, false><<<dim3(7, BATCH), 256, 0, stream>>>(
      dl, NN, NNODE, xwfrag, sXW, KC400, gcn1_b, dinv,
      hbuf, (long)NNODE * HID, HID, nullptr, 0, 0, nullptr, nullptr, NNODE, NNODE);
  mfgemm<false, true, false, false, true, false, false><<<dim3(7, BATCH), 256, 0, stream>>>(
      hbuf, (long)NNODE * HID, HID, w2frag, 0, 4, nullptr, dinv,
      nullptr, 0, 128, xwfrag, sXW, KC400, nullptr, nullptr, NNODE, HID);
  mfgemm<true, false, true, false, true, false, false><<<dim3(7, BATCH), 256, 0, stream>>>(
      dl, NN, NNODE, xwfrag, sXW, KC400, gcn2_b, dinv,
      hbuf, (long)NNODE * HID, HID, nullptr, 0, 0, nullptr, nullptr, NNODE, NNODE);

  head_k<<<BATCH, HID, 0, stream>>>(hbuf, fc_w, fc_b, out);
}

// Round 9
// 694.248 us; speedup vs baseline: 1.7890x; 1.7890x over previous
//
#include <hip/hip_runtime.h>
#include <hip/hip_bf16.h>
#include <math.h>

#define BATCH 128
#define NNODE 400
#define HID   128
#define NN    (NNODE*NNODE)      // 160000
#define KSEL  32000              // int(NN*0.2)
#define EQCAP 1024
#define EPSF  1e-9f
#define TSPLIT 8
#define SEG   (NN / TSPLIT)      // 20000
#define NT    7                  // ceil(400/64)
#define KC400 14                 // 448/32
#define FRAGS (KC400*4096)       // shorts per plane, K=400pad, N=128
#define PLA   57344              // shorts per plane: 4 kchunks * 28 ntiles * 512 (dec1_w: K=128, N=448pad)

// map float -> unsigned so that descending float order == descending unsigned order
__device__ __forceinline__ unsigned tokey(float f) {
  unsigned u = __float_as_uint(f);
  return (u & 0x80000000u) ? ~u : (u | 0x80000000u);
}

// fp32 -> bf16 (RNE) and back, as raw shorts
__device__ __forceinline__ short f2bf(float f) {
  unsigned u = __float_as_uint(f);
  u += 0x7fffu + ((u >> 16) & 1u);
  return (short)(u >> 16);
}
__device__ __forceinline__ float bf2f(short s) {
  return __uint_as_float(((unsigned)(unsigned short)s) << 16);
}

// fisher transform via hw log2: 0.5*ln((1+x+e)/(1-x+e))/dnm == (log2(a)-log2(b))*cmul
// cmul = 0.5*ln2/dnm.  v_log_f32 is ~1ulp -> xf perturbation ~1e-9 abs (safe).
__device__ __forceinline__ float xfhw(float xv, float cmul) {
  float la = __builtin_amdgcn_logf(1.0f + xv + EPSF);
  float lb = __builtin_amdgcn_logf(1.0f - xv + EPSF);
  return (la - lb) * cmul;
}

typedef __attribute__((ext_vector_type(8))) short s8v;
typedef __attribute__((ext_vector_type(4))) short s4v;
typedef __attribute__((ext_vector_type(4))) float f4v;

// ---------------------------------------------------------------------------
// 64x64-tile fp32 GEMM (VALU) — only G3 (residual, in-place) still uses this.
// ---------------------------------------------------------------------------
#define BK 16
#define LP 68

template<bool AT, bool BIAS, bool RES, bool RELU, bool TS>
__global__ void __launch_bounds__(256) gemm64(
    const float* __restrict__ A, long sA, int lda,
    const float* __restrict__ B, long sB, int ldb,
    const float* __restrict__ bias,
    const float* __restrict__ Res, long sRes,
    float* __restrict__ C, long sC, int ldc,
    int M, int Nc, int K)
{
  __shared__ float As[BK][LP];
  __shared__ float Bs[BK][LP];
  const int bz = blockIdx.z;
  A += (size_t)bz * sA;
  B += (size_t)bz * sB;
  C += (size_t)bz * sC;
  const float* Rp = RES ? (Res + (size_t)bz * sRes) : nullptr;

  const int n0 = blockIdx.x * 64;
  const int m0 = blockIdx.y * 64;
  const int tid = threadIdx.x;
  const int tx = tid & 15, ty = tid >> 4;
  const bool edgeM = (m0 + 64 > M);
  const bool edgeN = (n0 + 64 > Nc);

  float acc[4][4];
#pragma unroll
  for (int i = 0; i < 4; ++i)
#pragma unroll
    for (int j = 0; j < 4; ++j) acc[i][j] = 0.f;

  for (int k0 = 0; k0 < K; k0 += BK) {
    if (!AT) {
      const int m = tid & 63, g = tid >> 6;
      if (!edgeM) {
        const float4 v = *(const float4*)(A + (size_t)(m0 + m) * lda + k0 + 4 * g);
        As[4 * g + 0][m] = v.x; As[4 * g + 1][m] = v.y;
        As[4 * g + 2][m] = v.z; As[4 * g + 3][m] = v.w;
      } else {
        const int gm = m0 + m;
        const bool ok = gm < M;
#pragma unroll
        for (int j = 0; j < 4; ++j)
          As[4 * g + j][m] = ok ? A[(size_t)gm * lda + k0 + 4 * g + j] : 0.f;
      }
    } else {
      const int k = tid >> 4, mg = tid & 15;
      if (!edgeM) {
        const float4 v = *(const float4*)(A + (size_t)(k0 + k) * lda + m0 + 4 * mg);
        *(float4*)&As[k][4 * mg] = v;
      } else {
#pragma unroll
        for (int j = 0; j < 4; ++j) {
          const int gm = m0 + 4 * mg + j;
          As[k][4 * mg + j] = (gm < M) ? A[(size_t)(k0 + k) * lda + gm] : 0.f;
        }
      }
    }
    {
      const int k = tid >> 4, ng = tid & 15;
      if (!edgeN) {
        const float4 v = *(const float4*)(B + (size_t)(k0 + k) * ldb + n0 + 4 * ng);
        *(float4*)&Bs[k][4 * ng] = v;
      } else {
#pragma unroll
        for (int j = 0; j < 4; ++j) {
          const int gn = n0 + 4 * ng + j;
          Bs[k][4 * ng + j] = (gn < Nc) ? B[(size_t)(k0 + k) * ldb + gn] : 0.f;
        }
      }
    }
    __syncthreads();
#pragma unroll
    for (int kk = 0; kk < BK; ++kk) {
      const float4 a = *(const float4*)&As[kk][ty << 2];
      const float4 b = *(const float4*)&Bs[kk][tx << 2];
      const float av[4] = {a.x, a.y, a.z, a.w};
      const float bv[4] = {b.x, b.y, b.z, b.w};
#pragma unroll
      for (int i = 0; i < 4; ++i)
#pragma unroll
        for (int j = 0; j < 4; ++j) acc[i][j] += av[i] * bv[j];
    }
    __syncthreads();
  }

#pragma unroll
  for (int i = 0; i < 4; ++i) {
    const int m = m0 + (ty << 2) + i;
    if (m >= M) continue;
#pragma unroll
    for (int j = 0; j < 4; ++j) {
      const int n = n0 + (tx << 2) + j;
      if (n >= Nc) continue;
      float v = acc[i][j];
      if (BIAS) v += bias[n];
      const size_t loc = TS ? ((size_t)n * ldc + m) : ((size_t)m * ldc + n);
      if (RES) v += Rp[loc];
      if (RELU) v = fmaxf(v, 0.f);
      C[loc] = v;
    }
  }
}

// ---------------------------------------------------------------------------
// bsplit5: all 5 weight-fragment builds in ONE launch (blockIdx.y selects).
// W[K][N] fp32 -> MFMA B-fragment bf16 hi/lo planes (Kpad x Npad).
// ---------------------------------------------------------------------------
__global__ void bsplit5(
    const float* __restrict__ gcn1_w, const float* __restrict__ gcn2_w,
    const float* __restrict__ enc1_w, const float* __restrict__ enc2_w,
    const float* __restrict__ dec1_w,
    short* __restrict__ w1frag, short* __restrict__ w2frag,
    short* __restrict__ e1frag, short* __restrict__ e2frag,
    short* __restrict__ dfrag) {
  const float* W; short* out; int K, Kpad, N, Npad;
  switch (blockIdx.y) {
    case 0: W = gcn1_w; out = w1frag; K = NNODE; Kpad = 448; N = HID;   Npad = 128; break;
    case 1: W = gcn2_w; out = w2frag; K = HID;   Kpad = 128; N = HID;   Npad = 128; break;
    case 2: W = enc1_w; out = e1frag; K = NNODE; Kpad = 448; N = HID;   Npad = 128; break;
    case 3: W = enc2_w; out = e2frag; K = NNODE; Kpad = 448; N = HID;   Npad = 128; break;
    default: W = dec1_w; out = dfrag; K = HID;   Kpad = 128; N = NNODE; Npad = 448; break;
  }
  int t = blockIdx.x * 256 + threadIdx.x;
  if (t >= Kpad * Npad) return;
  int k = t / Npad, n = t - k * Npad;
  float v = (k < K && n < N) ? W[(size_t)k * N + n] : 0.f;
  short hi = f2bf(v);
  short lo = f2bf(v - bf2f(hi));
  int ntiles = Npad >> 4;
  size_t idx = (((size_t)(k >> 5) * ntiles + (n >> 4)) * 64
                + (((k >> 3) & 3) * 16 + (n & 15))) * 8 + (k & 7);
  size_t PL = (size_t)(Kpad >> 5) * ntiles * 512;
  out[idx] = hi;
  out[PL + idx] = lo;
}

// ---------------------------------------------------------------------------
// MFMA GEMM (bf16 split-3), N fixed 128.
// C[m,n] = act( [scl[m]*] sum_k A[m,k]*B[k,n] + bias[n] )
// AT: A[m][k]=Araw[k*lda+m].  FRAG: emit frag-ordered bf16 hi/lo (next B).
// TS: store transposed C^T[n][m] via LDS.
// XF (only with !AT): A is raw x; apply fisher transform (hw log2, folded
// 1/dnm) during staging and ALSO write the result to xfout (fuses xf_k into G1).
// ---------------------------------------------------------------------------
template<bool AT, bool FRAG, bool BIAS, bool RELU, bool SCL, bool TS, bool XF>
__global__ void __launch_bounds__(256) mfgemm(
    const float* __restrict__ A, long sA, int lda,
    const short* __restrict__ Bf, long sB, int kc,
    const float* __restrict__ bias,
    const float* __restrict__ scl,
    float* __restrict__ Cf, long sCf, int ldc,
    short* __restrict__ Cfrag, long sCfrag, int okc,
    const float* __restrict__ denomp, float* __restrict__ xfout,
    int M, int K)
{
  __shared__ float As[64][68];
  const int bz = blockIdx.y;
  A += (size_t)bz * sA;
  Bf += (size_t)bz * sB;
  if (SCL) scl += (size_t)bz * NNODE;
  if (!FRAG) Cf += (size_t)bz * sCf;
  else       Cfrag += (size_t)bz * sCfrag;
  if (XF) xfout += (size_t)bz * sA;
  // 0.5*ln2 / dnm (one scalar divide per thread, hoisted out of the loop)
  const float cmul = XF ? (0.34657359027997264f / denomp[bz]) : 0.f;

  const int tid = threadIdx.x;
  const int lane = tid & 63, wave = tid >> 6;
  const int wqm = wave >> 1, wqn = wave & 1;
  const int quad = lane >> 4, l15 = lane & 15;
  const int m0 = blockIdx.x * 64;

  f4v acc[2][4];
#pragma unroll
  for (int i = 0; i < 2; ++i)
#pragma unroll
    for (int j = 0; j < 4; ++j) acc[i][j] = (f4v){0.f, 0.f, 0.f, 0.f};

  const int nstage = (K + 63) >> 6;
  for (int st = 0; st < nstage; ++st) {
    const int k0 = st << 6;
    if (st) __syncthreads();
    if (!AT) {
      const int mrow = tid >> 4;
      const int k4 = (tid & 15) << 2;
#pragma unroll
      for (int u = 0; u < 4; ++u) {
        const int m = mrow + (u << 4);
        const int gm = m0 + m, gk = k0 + k4;
        float4 v = {0.f, 0.f, 0.f, 0.f};
        if (gm < M) {
          if (gk + 4 <= K) {
            float4 xv = *(const float4*)(A + (size_t)gm * lda + gk);
            if (XF) {
              v.x = xfhw(xv.x, cmul);
              v.y = xfhw(xv.y, cmul);
              v.z = xfhw(xv.z, cmul);
              v.w = xfhw(xv.w, cmul);
              *(float4*)(xfout + (size_t)gm * lda + gk) = v;
            } else v = xv;
          } else {
            float* pv = (float*)&v;
#pragma unroll
            for (int j = 0; j < 4; ++j)
              if (gk + j < K) {
                float xv = A[(size_t)gm * lda + gk + j];
                if (XF) {
                  pv[j] = xfhw(xv, cmul);
                  xfout[(size_t)gm * lda + gk + j] = pv[j];
                } else pv[j] = xv;
              }
          }
        }
        *(float4*)&As[m][k4] = v;
      }
    } else {
      const int kk = tid >> 4;
      const int m4 = (tid & 15) << 2;
#pragma unroll
      for (int u = 0; u < 4; ++u) {
        const int gk = k0 + kk + (u << 4);
        float4 v = {0.f, 0.f, 0.f, 0.f};
        if (gk < K) {
          if (m0 + m4 + 4 <= M) v = *(const float4*)(A + (size_t)gk * lda + m0 + m4);
          else {
            float* pv = (float*)&v;
#pragma unroll
            for (int j = 0; j < 4; ++j)
              if (m0 + m4 + j < M) pv[j] = A[(size_t)gk * lda + m0 + m4 + j];
          }
        }
        As[m4 + 0][kk + (u << 4)] = v.x;
        As[m4 + 1][kk + (u << 4)] = v.y;
        As[m4 + 2][kk + (u << 4)] = v.z;
        As[m4 + 3][kk + (u << 4)] = v.w;
      }
    }
    __syncthreads();

#pragma unroll
    for (int c2 = 0; c2 < 2; ++c2) {
      const int c = (st << 1) + c2;
      s8v bhi[4], blo[4];
#pragma unroll
      for (int nt = 0; nt < 4; ++nt) {
        const int ntg = (wqn << 2) + nt;
        const size_t off = (((size_t)c * 8 + ntg) * 64 + lane) * 8;
        bhi[nt] = *(const s8v*)(Bf + off);
        blo[nt] = *(const s8v*)(Bf + (size_t)kc * 4096 + off);
      }
#pragma unroll
      for (int mt = 0; mt < 2; ++mt) {
        const int row = (wqm << 5) + (mt << 4) + l15;
        const int kof = (c2 << 5) + (quad << 3);
        const f4v a0 = *(const f4v*)&As[row][kof];
        const f4v a1 = *(const f4v*)&As[row][kof + 4];
        s8v ah, al;
#pragma unroll
        for (int j = 0; j < 4; ++j) {
          short h0 = f2bf(a0[j]); ah[j] = h0; al[j] = f2bf(a0[j] - bf2f(h0));
          short h1 = f2bf(a1[j]); ah[j + 4] = h1; al[j + 4] = f2bf(a1[j] - bf2f(h1));
        }
#pragma unroll
        for (int nt = 0; nt < 4; ++nt) {
          acc[mt][nt] = __builtin_amdgcn_mfma_f32_16x16x32_bf16(ah, bhi[nt], acc[mt][nt], 0, 0, 0);
          acc[mt][nt] = __builtin_amdgcn_mfma_f32_16x16x32_bf16(ah, blo[nt], acc[mt][nt], 0, 0, 0);
          acc[mt][nt] = __builtin_amdgcn_mfma_f32_16x16x32_bf16(al, bhi[nt], acc[mt][nt], 0, 0, 0);
        }
      }
    }
  }

  // ---- epilogue ----
  if (TS) {
    for (int nh = 0; nh < 2; ++nh) {
      __syncthreads();
      if (wqn == nh) {
#pragma unroll
        for (int mt = 0; mt < 2; ++mt)
#pragma unroll
          for (int nt = 0; nt < 4; ++nt) {
            const int tn = (nt << 4) + l15;
            const int n  = (wqn << 6) + tn;
            const int mc = (wqm << 5) + (mt << 4) + (quad << 2);
            const f4v a = acc[mt][nt];
#pragma unroll
            for (int reg = 0; reg < 4; ++reg) {
              float v = a[reg];
              if (SCL) v *= scl[m0 + mc + reg];
              if (BIAS) v += bias[n];
              if (RELU) v = fmaxf(v, 0.f);
              As[tn][mc + reg] = v;
            }
          }
      }
      __syncthreads();
      const int row = tid >> 2, cq = tid & 3;
#pragma unroll
      for (int u = 0; u < 4; ++u) {
        const int col = (cq + (u << 2)) << 2;
        if (m0 + col + 4 <= M) {
          const float4 v = *(const float4*)&As[row][col];
          *(float4*)(Cf + (size_t)((nh << 6) + row) * ldc + m0 + col) = v;
        }
      }
    }
    return;
  }

#pragma unroll
  for (int mt = 0; mt < 2; ++mt) {
    const int mb = m0 + (wqm << 5) + (mt << 4) + (quad << 2);
#pragma unroll
    for (int nt = 0; nt < 4; ++nt) {
      const int n = (wqn << 6) + (nt << 4) + l15;
      const f4v a = acc[mt][nt];
      if (!FRAG) {
#pragma unroll
        for (int reg = 0; reg < 4; ++reg) {
          const int m = mb + reg;
          if (m < M) {
            float v = a[reg];
            if (SCL) v *= scl[m];
            if (BIAS) v += bias[n];
            if (RELU) v = fmaxf(v, 0.f);
            Cf[(size_t)m * ldc + n] = v;
          }
        }
      } else {
        s4v h4, l4;
#pragma unroll
        for (int reg = 0; reg < 4; ++reg) {
          const int m = mb + reg;
          float v = (m < M) ? (SCL ? a[reg] * scl[m] : a[reg]) : 0.f;
          short hh = f2bf(v);
          h4[reg] = hh; l4[reg] = f2bf(v - bf2f(hh));
        }
        const int chunkT = mb >> 5, quadT = (mb >> 3) & 3, jT0 = mb & 7;
        const size_t off = (((size_t)chunkT * 8 + (wqn << 2) + nt) * 64
                            + quadT * 16 + l15) * 8 + jT0;
        *(s4v*)(Cfrag + off) = h4;
        *(s4v*)(Cfrag + (size_t)okc * 4096 + off) = l4;
      }
    }
  }
}

// ---------------------------------------------------------------------------
// g4mf v7: proven-best structure (R6/R7, ~86 µs): d1-only epilogue, strided
// o1 A-loads, packed 2x-u16 12-bit LDS histogram (bits 31..20).
// ---------------------------------------------------------------------------
__global__ void __launch_bounds__(256) g4mf(
    const float* __restrict__ o1,    // [B][128][400] fp32 (out2b)
    const short* __restrict__ wfrag, // dec1_w frags, 2 planes of PLA
    const float* __restrict__ bias,  // dec1_b
    float* __restrict__ xf,          // in-place -> x2
    unsigned* __restrict__ ghist)    // [B][4096]
{
  __shared__ float D2[64][68];       // 17408 B
  __shared__ unsigned hist[2048];    // 4096 bins packed as 2x u16, 8192 B
  const int b = blockIdx.y;
  int p = blockIdx.x, bi = 0;
  while (p >= NT - bi) { p -= NT - bi; ++bi; }
  const int bj = bi + p;
  const int I0 = bi * 64, J0 = bj * 64;
  const bool diag = (bi == bj);

  o1 += (size_t)b * HID * NNODE;
  xf += (size_t)b * NN;
  unsigned* gh = ghist + (size_t)b * 4096;

  const int tid = threadIdx.x;
  const int lane = tid & 63, wave = tid >> 6;
  const int wq = wave & 1;
  const bool d1 = wave < 2;
  const int Bt = (d1 ? bj : bi) * 4;   // B ntile base (global, in wfrag)
  const int quad = lane >> 4, l15 = lane & 15;
  const int M0 = d1 ? I0 : J0;

  for (int i = tid; i < 2048; i += 256) hist[i] = 0u;

  f4v acc[2][4];
#pragma unroll
  for (int i = 0; i < 2; ++i)
#pragma unroll
    for (int j = 0; j < 4; ++j) acc[i][j] = (f4v){0.f, 0.f, 0.f, 0.f};

  const int gm0 = M0 + (wq << 5) + l15;    // mt=0 output row; mt=1 is +16

  for (int c = 0; c < 4; ++c) {
    const int k0 = c << 5;
    // ---- B frags from global (pre-split, frag-ordered) ----
    s8v bhi[4], blo[4];
#pragma unroll
    for (int nt = 0; nt < 4; ++nt) {
      const int ntg = Bt + nt;
      const size_t off = (((size_t)c * 28 + ntg) * 64 + lane) * 8;
      bhi[nt] = *(const s8v*)(wfrag + off);
      blo[nt] = *(const s8v*)(wfrag + PLA + off);
    }
    // ---- A frags straight from o1 columns (split in registers) ----
#pragma unroll
    for (int mt = 0; mt < 2; ++mt) {
      const int gm = gm0 + (mt << 4);
      float av[8];
      if (gm < NNODE) {
        const float* cp = o1 + (size_t)(k0 + (quad << 3)) * NNODE + gm;
#pragma unroll
        for (int j = 0; j < 8; ++j) av[j] = cp[(size_t)j * NNODE];
      } else {
#pragma unroll
        for (int j = 0; j < 8; ++j) av[j] = 0.f;
      }
      s8v ah, al;
#pragma unroll
      for (int j = 0; j < 8; ++j) {
        short h = f2bf(av[j]); ah[j] = h; al[j] = f2bf(av[j] - bf2f(h));
      }
#pragma unroll
      for (int nt = 0; nt < 4; ++nt) {
        acc[mt][nt] = __builtin_amdgcn_mfma_f32_16x16x32_bf16(ah, bhi[nt], acc[mt][nt], 0, 0, 0);
        acc[mt][nt] = __builtin_amdgcn_mfma_f32_16x16x32_bf16(ah, blo[nt], acc[mt][nt], 0, 0, 0);
        acc[mt][nt] = __builtin_amdgcn_mfma_f32_16x16x32_bf16(al, bhi[nt], acc[mt][nt], 0, 0, 0);
      }
    }
  }

  // waves 2/3: dump delta2[m'][n'] to LDS
  if (!d1) {
#pragma unroll
    for (int mt = 0; mt < 2; ++mt) {
      const int mb = (wq << 5) + (mt << 4) + (quad << 2);
#pragma unroll
      for (int nt = 0; nt < 4; ++nt) {
        const int nn = (nt << 4) + l15;
        const f4v a = acc[mt][nt];
#pragma unroll
        for (int reg = 0; reg < 4; ++reg) D2[mb + reg][nn] = a[reg];
      }
    }
  }
  __syncthreads();

  // waves 0/1: form x2 tile (I,J), write both (I,J) and (J,I), histogram
  if (d1) {
    const unsigned w = diag ? 1u : 2u;
#pragma unroll
    for (int mt = 0; mt < 2; ++mt) {
      const int a0 = (wq << 5) + (mt << 4) + (quad << 2);
#pragma unroll
      for (int nt = 0; nt < 4; ++nt) {
        const int nn = (nt << 4) + l15;
        const int gj = J0 + nn;
        const f4v d1v = acc[mt][nt];
        const f4v d2t = *(const f4v*)&D2[nn][a0];
        f4v vv;
#pragma unroll
        for (int reg = 0; reg < 4; ++reg) {
          const int gi = I0 + a0 + reg;
          float v = 0.f;
          if (gi < NNODE && gj < NNODE) {
            v = xf[(size_t)gi * NNODE + gj];
            if (gi != gj)
              v += 0.5f * (d1v[reg] + d2t[reg] + bias[gj] + bias[gi]);
            const unsigned bin = tokey(v) >> 20;
            atomicAdd(&hist[bin >> 1], w << ((bin & 1) << 4));
          }
          vv[reg] = v;
        }
#pragma unroll
        for (int reg = 0; reg < 4; ++reg) {
          const int gi = I0 + a0 + reg;
          if (gi < NNODE && gj < NNODE) xf[(size_t)gi * NNODE + gj] = vv[reg];
        }
        if (!diag && gj < NNODE && (I0 + a0 + 4 <= NNODE)) {
          *(float4*)(xf + (size_t)gj * NNODE + I0 + a0) = *(float4*)&vv;
        }
      }
    }
  }
  __syncthreads();
  for (int i = tid; i < 2048; i += 256) {
    const unsigned v = hist[i];
    const unsigned lo = v & 0xFFFFu, hi = v >> 16;
    if (lo) atomicAdd(&gh[2 * i], lo);
    if (hi) atomicAdd(&gh[2 * i + 1], hi);
  }
}

// ---------------------------------------------------------------------------
// tzd: fused init (ghist 4096-bin zero, per-sample state, deg zero) + denom.
// ---------------------------------------------------------------------------
__global__ void tzd(const float* __restrict__ x, unsigned* __restrict__ ghist,
                    unsigned* __restrict__ sprefix, int* __restrict__ sk,
                    int* __restrict__ eqcnt, float* __restrict__ deg,
                    float* __restrict__ denom, unsigned* __restrict__ ccnt2) {
  int t = blockIdx.x * 256 + threadIdx.x;
  if (t < BATCH * 4096) ghist[t] = 0u;
  if (t < BATCH) {
    sprefix[t] = 0u; sk[t] = KSEL; eqcnt[t] = 0;
    float v = x[(size_t)t * NN];
    denom[t] = 0.5f * logf((1.0f + v + EPSF) / (1.0f - v + EPSF));
  }
  if (t < BATCH * TSPLIT) ccnt2[t] = 0u;
  if (t < BATCH * NNODE) deg[t] = 0.f;
}

// ---------------------------------------------------------------------------
// thistA: pass A of radix select — bins = bits 19..8 (4096), prefix = top 12.
// ALSO compacts matching KEYS into this block's PRIVATE segment
// cand[b*NN + sb*SEG ...], allocated via a block-local LDS counter
// (NO global atomics in the hot loop — R8's cross-XCD cache-line ping-pong
// on ccnt[] serialized the whole kernel). One plain global store of the
// count per block at the end. Order is arbitrary; downstream histogram
// counts are order-independent, so selection is unchanged.
// ---------------------------------------------------------------------------
__global__ void __launch_bounds__(256) thistA(const float* __restrict__ x2,
                                              const unsigned* __restrict__ sprefix,
                                              unsigned* __restrict__ ghist,
                                              unsigned* __restrict__ cand,
                                              unsigned* __restrict__ ccnt2) {
  __shared__ unsigned h[4096];
  __shared__ unsigned lcnt;
  const int b  = blockIdx.y;
  const int sb = blockIdx.x;
  const int tid = threadIdx.x;
  for (int i = tid; i < 4096; i += 256) h[i] = 0u;
  if (tid == 0) lcnt = 0u;
  __syncthreads();

  const unsigned prefix = sprefix[b];
  unsigned* cb = cand + (size_t)b * NN + (size_t)sb * SEG;   // private segment
  const float4* p4 = (const float4*)(x2 + (size_t)b * NN);
  const int i0 = sb * (SEG / 4), i1 = i0 + (SEG / 4);
  for (int i = i0 + tid; i < i1; i += 256) {
    float4 v = p4[i];
    unsigned kk[4] = {tokey(v.x), tokey(v.y), tokey(v.z), tokey(v.w)};
#pragma unroll
    for (int q = 0; q < 4; ++q) {
      const unsigned key = kk[q];
      if ((key & 0xFFF00000u) == prefix) {
        atomicAdd(&h[(key >> 8) & 4095u], 1u);
        const unsigned pos = atomicAdd(&lcnt, 1u);   // LDS atomic: cheap
        cb[pos] = key;
      }
    }
  }
  __syncthreads();
  for (int i = tid; i < 4096; i += 256) {
    unsigned s = h[i];
    if (s) atomicAdd(&ghist[(size_t)b * 4096 + i], s);
  }
  if (tid == 0) ccnt2[b * TSPLIT + sb] = lcnt;       // plain store, no atomic
}

// ---------------------------------------------------------------------------
// tpick12<SH>: select the 12-bit bin from a 4096-bin histogram (two-level
// scan: 256 chunk sums, then <=16-bin walk). Updates sprefix/sk; zeroes ghist.
// ---------------------------------------------------------------------------
template<int SH>
__global__ void __launch_bounds__(256) tpick12(unsigned* __restrict__ ghist,
                                               unsigned* __restrict__ sprefix,
                                               int* __restrict__ sk) {
  const int b = blockIdx.x;
  __shared__ unsigned h[4096];
  __shared__ unsigned csum[256];
  unsigned* gh = ghist + (size_t)b * 4096;
  unsigned local = 0;
#pragma unroll
  for (int u = 0; u < 16; ++u) {
    unsigned v = gh[threadIdx.x * 16 + u];
    h[threadIdx.x * 16 + u] = v;
    local += v;
  }
  csum[threadIdx.x] = local;
  __syncthreads();
  if (threadIdx.x == 0) {
    int k = sk[b];
    int bin = 0;
    for (int ch = 255; ch >= 0; --ch) {
      int S = (int)csum[ch];
      if (S >= k) {
        for (int bb = ch * 16 + 15; bb >= ch * 16; --bb) {
          int c = (int)h[bb];
          if (c >= k) { bin = bb; break; }
          k -= c;
        }
        break;
      }
      k -= S;
    }
    sprefix[b] = sprefix[b] | ((unsigned)bin << SH);
    sk[b] = k;
  }
#pragma unroll
  for (int u = 0; u < 16; ++u) gh[threadIdx.x * 16 + u] = 0u;
}

// ---------------------------------------------------------------------------
// thistC: final 8-bit pass over the 8 per-block candidate segments instead
// of re-scanning all 82 MB. One block per sample; filters on the 24-bit
// prefix, builds the 256-bin histogram in LDS, picks tau/rrem directly.
// ---------------------------------------------------------------------------
__global__ void __launch_bounds__(256) thistC(const unsigned* __restrict__ cand,
                                              const unsigned* __restrict__ ccnt2,
                                              const unsigned* __restrict__ sprefix,
                                              const int* __restrict__ sk,
                                              unsigned* __restrict__ tau,
                                              int* __restrict__ rrem) {
  __shared__ unsigned h[8][256];
  const int b = blockIdx.x;
  const int tid = threadIdx.x;
  for (int i = tid; i < 8 * 256; i += 256) ((unsigned*)h)[i] = 0u;
  __syncthreads();
  const unsigned prefix = sprefix[b];           // top 24 bits set
  const int rep = tid & 7;
  for (int sb = 0; sb < TSPLIT; ++sb) {
    const unsigned n = ccnt2[b * TSPLIT + sb];
    const unsigned* cp = cand + (size_t)b * NN + (size_t)sb * SEG;
    for (unsigned i = tid; i < n; i += 256) {
      const unsigned key = cp[i];
      if ((key & 0xFFFFFF00u) == prefix) atomicAdd(&h[rep][key & 255u], 1u);
    }
  }
  __syncthreads();
  if (tid < 256) {
    const unsigned s = h[0][tid] + h[1][tid] + h[2][tid] + h[3][tid]
                     + h[4][tid] + h[5][tid] + h[6][tid] + h[7][tid];
    h[0][tid] = s;
  }
  __syncthreads();
  if (tid == 0) {
    int k = sk[b];
    unsigned byte = 0u;
    for (int bin = 255; bin >= 0; --bin) {
      int c = (int)h[0][bin];
      if (c >= k) { byte = (unsigned)bin; break; }
      k -= c;
    }
    tau[b] = prefix | byte;
    rrem[b] = k;
  }
}

// ---------------------------------------------------------------------------
// build_kc: A = x2 masked (key > tau), tie gathering, AND per-column sums
// (fuses old deg_k). Block = (16-row group, sample). deg zeroed in tzd.
// ---------------------------------------------------------------------------
__global__ void __launch_bounds__(256) build_kc(
    const float* __restrict__ x2, const unsigned* __restrict__ tau,
    float* __restrict__ A, float* __restrict__ deg,
    int* __restrict__ eqcnt, int* __restrict__ eqidx) {
  __shared__ float cs[NNODE];
  const int b = blockIdx.y, rg = blockIdx.x;
  const int tid = threadIdx.x;
  for (int i = tid; i < NNODE; i += 256) cs[i] = 0.f;
  __syncthreads();
  const unsigned tk = tau[b];
  const size_t base = (size_t)b * NN + (size_t)rg * 6400;
  for (int u = 0; u < 25; ++u) {
    const int t = u * 256 + tid;          // < 6400 = 16 rows * 400 cols
    const float v = x2[base + t];
    const unsigned key = tokey(v);
    const float a = (key > tk) ? v : 0.f;
    A[base + t] = a;
    if (key == tk) {
      int p = atomicAdd(&eqcnt[b], 1);
      if (p < EQCAP) eqidx[b * EQCAP + p] = rg * 6400 + t;
    }
    if (a != 0.f) atomicAdd(&cs[t % NNODE], a);
  }
  __syncthreads();
  for (int j = tid; j < NNODE; j += 256)
    if (cs[j] != 0.f) atomicAdd(&deg[b * NNODE + j], cs[j]);
}

// ---------------------------------------------------------------------------
// eqdinv: fused tie-fix + diag-fill + dinv, one block per sample.
// ---------------------------------------------------------------------------
__global__ void __launch_bounds__(256) eqdinv(
    float* __restrict__ A, const float* __restrict__ x2,
    float* __restrict__ deg, float* __restrict__ dinv,
    const int* __restrict__ eqcnt, const int* __restrict__ eqidx,
    const int* __restrict__ rrem) {
  const int b = blockIdx.x;
  int cnt = eqcnt[b]; if (cnt > EQCAP) cnt = EQCAP;
  const int r = rrem[b];
  for (int t = threadIdx.x; t < cnt; t += 256) {
    int idx = eqidx[b * EQCAP + t];
    int rank = 0;
    for (int u = 0; u < cnt; ++u) rank += (eqidx[b * EQCAP + u] < idx) ? 1 : 0;
    if (rank < r) {
      float v = x2[(size_t)b * NN + idx];
      A[(size_t)b * NN + idx] = v;
      atomicAdd(&deg[b * NNODE + idx % NNODE], v);
    }
  }
  __syncthreads();
  for (int j = threadIdx.x; j < NNODE; j += 256) {
    float d = deg[b * NNODE + j];
    size_t o = (size_t)b * NN + (size_t)j * NNODE + j;
    if (A[o] == 0.f) { A[o] = 1.0f; d += 1.0f; }
    dinv[b * NNODE + j] = (d == 0.f) ? 0.f : 1.0f / sqrtf(d);
  }
}

__global__ void head_k(const float* __restrict__ h2, const float* __restrict__ fc_w,
                       const float* __restrict__ fc_b, float* __restrict__ out) {
  int b = blockIdx.x;
  int f = threadIdx.x;
  float s = 0.f;
  const float* p = h2 + (size_t)b * NNODE * HID + f;
  for (int j = 0; j < NNODE; ++j) s += p[(size_t)j * HID];
  float pv = fmaxf(s / (float)NNODE, 0.f);
  __shared__ float r0[128], r1[128];
  r0[f] = pv * fc_w[f * 2 + 0];
  r1[f] = pv * fc_w[f * 2 + 1];
  __syncthreads();
  for (int sft = 64; sft > 0; sft >>= 1) {
    if (f < sft) { r0[f] += r0[f + sft]; r1[f] += r1[f + sft]; }
    __syncthreads();
  }
  if (f == 0) {
    out[b * 2 + 0] = r0[0] + fc_b[0];
    out[b * 2 + 1] = r1[0] + fc_b[1];
  }
}

// ---------------------------------------------------------------------------
extern "C" void kernel_launch(void* const* d_in, const int* in_sizes, int n_in,
                              void* d_out, int out_size, void* d_ws, size_t ws_size,
                              hipStream_t stream) {
  const float* x      = (const float*)d_in[0];
  const float* enc1_w = (const float*)d_in[2];
  const float* enc1_b = (const float*)d_in[3];
  const float* enc2_w = (const float*)d_in[4];
  const float* enc2_b = (const float*)d_in[5];
  const float* dec2_w = (const float*)d_in[6];
  const float* dec2_b = (const float*)d_in[7];
  const float* dec1_w = (const float*)d_in[8];
  const float* dec1_b = (const float*)d_in[9];
  const float* gcn1_w = (const float*)d_in[10];
  const float* gcn1_b = (const float*)d_in[11];
  const float* gcn2_w = (const float*)d_in[12];
  const float* gcn2_b = (const float*)d_in[13];
  const float* fc_w   = (const float*)d_in[14];
  const float* fc_b   = (const float*)d_in[15];
  float* out = (float*)d_out;
  (void)in_sizes; (void)n_in; (void)out_size; (void)ws_size;

  float* ws = (float*)d_ws;
  size_t off = 0;
  auto take = [&](size_t n) { float* p = ws + off; off += (n + 63) & ~(size_t)63; return p; };
  float* xf   = take((size_t)BATCH * NN);          // xf -> x2 (in place)
  float* dl   = take((size_t)BATCH * NN);          // cand keys (radix), then A (sparsified)
  float* o1   = take((size_t)BATCH * HID * NNODE); // out1 -> out2b; later xwfrag alias
  float* o2   = take((size_t)BATCH * HID * HID);
  float* hbuf = take((size_t)BATCH * NNODE * HID); // h -> h2
  float* denom = take(BATCH);
  float* dinv  = take((size_t)BATCH * NNODE);
  float* deg   = take((size_t)BATCH * NNODE);
  unsigned* tau = (unsigned*)take(BATCH);
  int* rrem  = (int*)take(BATCH);
  int* eqcnt = (int*)take(BATCH);
  int* eqidx = (int*)take((size_t)BATCH * EQCAP);
  unsigned* ghist   = (unsigned*)take((size_t)BATCH * 4096);   // 12-bit bins
  unsigned* sprefix = (unsigned*)take(BATCH);
  int*      sk      = (int*)take(BATCH);
  unsigned* ccnt2   = (unsigned*)take((size_t)BATCH * TSPLIT); // per-(b,sb) counts
  short* w1frag = (short*)take((size_t)FRAGS + 64);          // gcn1_w, 2 planes K448
  short* w2frag = (short*)take((size_t)4 * 4096 + 64);       // gcn2_w, 2 planes K128
  short* e1frag = (short*)take((size_t)FRAGS + 64);          // enc1_w
  short* e2frag = (short*)take((size_t)FRAGS + 64);          // enc2_w
  short* dfrag  = (short*)take((size_t)PLA + 64);            // dec1_w (2*PLA shorts)
  short* xwfrag = (short*)o1;          // aliases dead o1 (post-g4mf)
  unsigned* cand = (unsigned*)dl;      // candidate keys, dead before build_kc
  const long sXW = 2L * FRAGS;

  tzd<<<2048, 256, 0, stream>>>(x, ghist, sprefix, sk, eqcnt, deg, denom, ccnt2);
  bsplit5<<<dim3(224, 5), 256, 0, stream>>>(gcn1_w, gcn2_w, enc1_w, enc2_w, dec1_w,
                                            w1frag, w2frag, e1frag, e2frag, dfrag);

  // G1 (+fused xf): reads raw x, computes/stores xf, o1 = (relu(xf@enc1_w+b))^T
  mfgemm<false, false, true, true, false, true, true><<<dim3(7, BATCH), 256, 0, stream>>>(
      x, NN, NNODE, e1frag, 0, KC400, enc1_b, nullptr,
      o1, (long)HID * NNODE, NNODE, nullptr, 0, 0, denom, xf, NNODE, NNODE);
  // G2: o2 = relu(o1 @ enc2_w + b)
  mfgemm<false, false, true, true, false, false, false><<<dim3(2, BATCH), 256, 0, stream>>>(
      o1, (long)HID * NNODE, NNODE, e2frag, 0, KC400, enc2_b, nullptr,
      o2, (long)HID * HID, HID, nullptr, 0, 0, nullptr, nullptr, HID, NNODE);
  // G3: out2b = relu(o2 @ dec2_w + b + o1), in-place (fp32)
  gemm64<false, true, true, true, false><<<dim3(7, 2, BATCH), 256, 0, stream>>>(
      o2, (long)HID * HID, HID, dec2_w, 0, NNODE, dec2_b,
      o1, (long)HID * NNODE, o1, (long)HID * NNODE, NNODE, HID, NNODE, HID);

  // fused delta + symmetrize + x2 + pass-0 12-bit histogram (packed LDS)
  g4mf<<<dim3(NT * (NT + 1) / 2, BATCH), 256, 0, stream>>>(o1, dfrag, dec1_b, xf, ghist);

  // radix select: 12 + 12 + 8 bits; pass B runs on the compact candidate list
  tpick12<20><<<BATCH, 256, 0, stream>>>(ghist, sprefix, sk);
  thistA<<<dim3(TSPLIT, BATCH), 256, 0, stream>>>(xf, sprefix, ghist, cand, ccnt2);
  tpick12<8><<<BATCH, 256, 0, stream>>>(ghist, sprefix, sk);
  thistC<<<BATCH, 256, 0, stream>>>(cand, ccnt2, sprefix, sk, tau, rrem);

  // A build + column sums (fused deg), then fused tie-fix + diag-fill + dinv
  build_kc<<<dim3(25, BATCH), 256, 0, stream>>>(xf, tau, dl, deg, eqcnt, eqidx);
  eqdinv<<<BATCH, 256, 0, stream>>>(dl, xf, deg, dinv, eqcnt, eqidx, rrem);

  // ---- post-top-k GCN: MFMA bf16 split-3 ----
  mfgemm<false, true, false, false, true, false, false><<<dim3(7, BATCH), 256, 0, stream>>>(
      xf, NN, NNODE, w1frag, 0, KC400, nullptr, dinv,
      nullptr, 0, 128, xwfrag, sXW, KC400, nullptr, nullptr, NNODE, NNODE);
  mfgemm<true, false, true, true, true, false, false><<<dim3(7, BATCH), 256, 0, stream>>>(
      dl, NN, NNODE, xwfrag, sXW, KC400, gcn1_b, dinv,
      hbuf, (long)NNODE * HID, HID, nullptr, 0, 0, nullptr, nullptr, NNODE, NNODE);
  mfgemm<false, true, false, false, true, false, false><<<dim3(7, BATCH), 256, 0, stream>>>(
      hbuf, (long)NNODE * HID, HID, w2frag, 0, 4, nullptr, dinv,
      nullptr, 0, 128, xwfrag, sXW, KC400, nullptr, nullptr, NNODE, HID);
  mfgemm<true, false, true, false, true, false, false><<<dim3(7, BATCH), 256, 0, stream>>>(
      dl, NN, NNODE, xwfrag, sXW, KC400, gcn2_b, dinv,
      hbuf, (long)NNODE * HID, HID, nullptr, 0, 0, nullptr, nullptr, NNODE, NNODE);

  head_k<<<BATCH, HID, 0, stream>>>(hbuf, fc_w, fc_b, out);
}

// Round 10
// 634.914 us; speedup vs baseline: 1.9561x; 1.0935x over previous
//
#include <hip/hip_runtime.h>
#include <hip/hip_bf16.h>
#include <math.h>

#define BATCH 128
#define NNODE 400
#define HID   128
#define NN    (NNODE*NNODE)      // 160000
#define KSEL  32000              // int(NN*0.2)
#define EQCAP 1024
#define EPSF  1e-9f
#define TSPLIT 8
#define SEG   (NN / TSPLIT)      // 20000
#define NT    7                  // ceil(400/64)
#define KC400 14                 // 448/32
#define FRAGS (KC400*4096)       // shorts per plane, K=400pad, N=128
#define PLA   57344              // shorts per plane: 4 kchunks * 28 ntiles * 512 (dec1_w: K=128, N=448pad)

// map float -> unsigned so that descending float order == descending unsigned order
__device__ __forceinline__ unsigned tokey(float f) {
  unsigned u = __float_as_uint(f);
  return (u & 0x80000000u) ? ~u : (u | 0x80000000u);
}

// fp32 -> bf16 (RNE) and back, as raw shorts
__device__ __forceinline__ short f2bf(float f) {
  unsigned u = __float_as_uint(f);
  u += 0x7fffu + ((u >> 16) & 1u);
  return (short)(u >> 16);
}
__device__ __forceinline__ float bf2f(short s) {
  return __uint_as_float(((unsigned)(unsigned short)s) << 16);
}

// fisher transform via hw log2: 0.5*ln((1+x+e)/(1-x+e))/dnm == (log2(a)-log2(b))*cmul
__device__ __forceinline__ float xfhw(float xv, float cmul) {
  float la = __builtin_amdgcn_logf(1.0f + xv + EPSF);
  float lb = __builtin_amdgcn_logf(1.0f - xv + EPSF);
  return (la - lb) * cmul;
}

typedef __attribute__((ext_vector_type(8))) short s8v;
typedef __attribute__((ext_vector_type(4))) short s4v;
typedef __attribute__((ext_vector_type(4))) float f4v;

// ---------------------------------------------------------------------------
// 64x64-tile fp32 GEMM (VALU) — only G3 (residual, in-place) still uses this.
// ---------------------------------------------------------------------------
#define BK 16
#define LP 68

template<bool AT, bool BIAS, bool RES, bool RELU, bool TS>
__global__ void __launch_bounds__(256) gemm64(
    const float* __restrict__ A, long sA, int lda,
    const float* __restrict__ B, long sB, int ldb,
    const float* __restrict__ bias,
    const float* __restrict__ Res, long sRes,
    float* __restrict__ C, long sC, int ldc,
    int M, int Nc, int K)
{
  __shared__ float As[BK][LP];
  __shared__ float Bs[BK][LP];
  const int bz = blockIdx.z;
  A += (size_t)bz * sA;
  B += (size_t)bz * sB;
  C += (size_t)bz * sC;
  const float* Rp = RES ? (Res + (size_t)bz * sRes) : nullptr;

  const int n0 = blockIdx.x * 64;
  const int m0 = blockIdx.y * 64;
  const int tid = threadIdx.x;
  const int tx = tid & 15, ty = tid >> 4;
  const bool edgeM = (m0 + 64 > M);
  const bool edgeN = (n0 + 64 > Nc);

  float acc[4][4];
#pragma unroll
  for (int i = 0; i < 4; ++i)
#pragma unroll
    for (int j = 0; j < 4; ++j) acc[i][j] = 0.f;

  for (int k0 = 0; k0 < K; k0 += BK) {
    if (!AT) {
      const int m = tid & 63, g = tid >> 6;
      if (!edgeM) {
        const float4 v = *(const float4*)(A + (size_t)(m0 + m) * lda + k0 + 4 * g);
        As[4 * g + 0][m] = v.x; As[4 * g + 1][m] = v.y;
        As[4 * g + 2][m] = v.z; As[4 * g + 3][m] = v.w;
      } else {
        const int gm = m0 + m;
        const bool ok = gm < M;
#pragma unroll
        for (int j = 0; j < 4; ++j)
          As[4 * g + j][m] = ok ? A[(size_t)gm * lda + k0 + 4 * g + j] : 0.f;
      }
    } else {
      const int k = tid >> 4, mg = tid & 15;
      if (!edgeM) {
        const float4 v = *(const float4*)(A + (size_t)(k0 + k) * lda + m0 + 4 * mg);
        *(float4*)&As[k][4 * mg] = v;
      } else {
#pragma unroll
        for (int j = 0; j < 4; ++j) {
          const int gm = m0 + 4 * mg + j;
          As[k][4 * mg + j] = (gm < M) ? A[(size_t)(k0 + k) * lda + gm] : 0.f;
        }
      }
    }
    {
      const int k = tid >> 4, ng = tid & 15;
      if (!edgeN) {
        const float4 v = *(const float4*)(B + (size_t)(k0 + k) * ldb + n0 + 4 * ng);
        *(float4*)&Bs[k][4 * ng] = v;
      } else {
#pragma unroll
        for (int j = 0; j < 4; ++j) {
          const int gn = n0 + 4 * ng + j;
          Bs[k][4 * ng + j] = (gn < Nc) ? B[(size_t)(k0 + k) * ldb + gn] : 0.f;
        }
      }
    }
    __syncthreads();
#pragma unroll
    for (int kk = 0; kk < BK; ++kk) {
      const float4 a = *(const float4*)&As[kk][ty << 2];
      const float4 b = *(const float4*)&Bs[kk][tx << 2];
      const float av[4] = {a.x, a.y, a.z, a.w};
      const float bv[4] = {b.x, b.y, b.z, b.w};
#pragma unroll
      for (int i = 0; i < 4; ++i)
#pragma unroll
        for (int j = 0; j < 4; ++j) acc[i][j] += av[i] * bv[j];
    }
    __syncthreads();
  }

#pragma unroll
  for (int i = 0; i < 4; ++i) {
    const int m = m0 + (ty << 2) + i;
    if (m >= M) continue;
#pragma unroll
    for (int j = 0; j < 4; ++j) {
      const int n = n0 + (tx << 2) + j;
      if (n >= Nc) continue;
      float v = acc[i][j];
      if (BIAS) v += bias[n];
      const size_t loc = TS ? ((size_t)n * ldc + m) : ((size_t)m * ldc + n);
      if (RES) v += Rp[loc];
      if (RELU) v = fmaxf(v, 0.f);
      C[loc] = v;
    }
  }
}

// ---------------------------------------------------------------------------
// bsplit5: all 5 weight-fragment builds in ONE launch (blockIdx.y selects).
// ---------------------------------------------------------------------------
__global__ void bsplit5(
    const float* __restrict__ gcn1_w, const float* __restrict__ gcn2_w,
    const float* __restrict__ enc1_w, const float* __restrict__ enc2_w,
    const float* __restrict__ dec1_w,
    short* __restrict__ w1frag, short* __restrict__ w2frag,
    short* __restrict__ e1frag, short* __restrict__ e2frag,
    short* __restrict__ dfrag) {
  const float* W; short* out; int K, Kpad, N, Npad;
  switch (blockIdx.y) {
    case 0: W = gcn1_w; out = w1frag; K = NNODE; Kpad = 448; N = HID;   Npad = 128; break;
    case 1: W = gcn2_w; out = w2frag; K = HID;   Kpad = 128; N = HID;   Npad = 128; break;
    case 2: W = enc1_w; out = e1frag; K = NNODE; Kpad = 448; N = HID;   Npad = 128; break;
    case 3: W = enc2_w; out = e2frag; K = NNODE; Kpad = 448; N = HID;   Npad = 128; break;
    default: W = dec1_w; out = dfrag; K = HID;   Kpad = 128; N = NNODE; Npad = 448; break;
  }
  int t = blockIdx.x * 256 + threadIdx.x;
  if (t >= Kpad * Npad) return;
  int k = t / Npad, n = t - k * Npad;
  float v = (k < K && n < N) ? W[(size_t)k * N + n] : 0.f;
  short hi = f2bf(v);
  short lo = f2bf(v - bf2f(hi));
  int ntiles = Npad >> 4;
  size_t idx = (((size_t)(k >> 5) * ntiles + (n >> 4)) * 64
                + (((k >> 3) & 3) * 16 + (n & 15))) * 8 + (k & 7);
  size_t PL = (size_t)(Kpad >> 5) * ntiles * 512;
  out[idx] = hi;
  out[PL + idx] = lo;
}

// ---------------------------------------------------------------------------
// MFMA GEMM (bf16 split-3), N fixed 128.
// AT: A[m][k]=Araw[k*lda+m].  FRAG: emit frag-ordered bf16 hi/lo (next B).
// TS: store transposed C^T[n][m] via LDS.  XF: fisher transform fused (G1).
// MASK (!AT only): while staging x2, ALSO write A=mask(x2,tau) to Aout,
//   gather ties into eqidx, accumulate per-column sums -> deg (fuses the
//   old build_kc; each x2 element is staged exactly once across blocks).
// DSCL (AT only): multiply the staged A element by dsclp[gk] (folds the
//   dinv[i] row factor of An into the gather GEMM's A operand).
// ---------------------------------------------------------------------------
template<bool AT, bool FRAG, bool BIAS, bool RELU, bool SCL, bool TS, bool XF,
         bool MASK, bool DSCL>
__global__ void __launch_bounds__(256) mfgemm(
    const float* __restrict__ A, long sA, int lda,
    const short* __restrict__ Bf, long sB, int kc,
    const float* __restrict__ bias,
    const float* __restrict__ scl,
    float* __restrict__ Cf, long sCf, int ldc,
    short* __restrict__ Cfrag, long sCfrag, int okc,
    const float* __restrict__ denomp, float* __restrict__ xfout,
    const unsigned* __restrict__ taup, float* __restrict__ Aout,
    float* __restrict__ degp, int* __restrict__ eqcntp,
    int* __restrict__ eqidxp, const float* __restrict__ dsclp,
    int M, int K)
{
  __shared__ float As[64][68];
  __shared__ float cs[MASK ? NNODE : 1];
  const int bz = blockIdx.y;
  A += (size_t)bz * sA;
  Bf += (size_t)bz * sB;
  if (SCL) scl += (size_t)bz * NNODE;
  if (!FRAG) Cf += (size_t)bz * sCf;
  else       Cfrag += (size_t)bz * sCfrag;
  if (XF) xfout += (size_t)bz * sA;
  const float cmul = XF ? (0.34657359027997264f / denomp[bz]) : 0.f;
  const unsigned tk = MASK ? taup[bz] : 0u;
  if (MASK) { Aout += (size_t)bz * NN; degp += (size_t)bz * NNODE;
              eqcntp += bz; eqidxp += (size_t)bz * EQCAP; }
  if (DSCL) dsclp += (size_t)bz * NNODE;

  const int tid = threadIdx.x;
  const int lane = tid & 63, wave = tid >> 6;
  const int wqm = wave >> 1, wqn = wave & 1;
  const int quad = lane >> 4, l15 = lane & 15;
  const int m0 = blockIdx.x * 64;

  if (MASK) {
    for (int i = tid; i < NNODE; i += 256) cs[i] = 0.f;
    __syncthreads();
  }

  f4v acc[2][4];
#pragma unroll
  for (int i = 0; i < 2; ++i)
#pragma unroll
    for (int j = 0; j < 4; ++j) acc[i][j] = (f4v){0.f, 0.f, 0.f, 0.f};

  const int nstage = (K + 63) >> 6;
  for (int st = 0; st < nstage; ++st) {
    const int k0 = st << 6;
    if (st) __syncthreads();
    if (!AT) {
      const int mrow = tid >> 4;
      const int k4 = (tid & 15) << 2;
#pragma unroll
      for (int u = 0; u < 4; ++u) {
        const int m = mrow + (u << 4);
        const int gm = m0 + m, gk = k0 + k4;
        float4 v = {0.f, 0.f, 0.f, 0.f};
        if (gm < M) {
          if (gk + 4 <= K) {
            float4 xv = *(const float4*)(A + (size_t)gm * lda + gk);
            if (XF) {
              v.x = xfhw(xv.x, cmul);
              v.y = xfhw(xv.y, cmul);
              v.z = xfhw(xv.z, cmul);
              v.w = xfhw(xv.w, cmul);
              *(float4*)(xfout + (size_t)gm * lda + gk) = v;
            } else v = xv;
            if (MASK) {
              float4 av;
              float* pa = (float*)&av;
              const float* px = (const float*)&v;
#pragma unroll
              for (int j = 0; j < 4; ++j) {
                const unsigned key = tokey(px[j]);
                float a = (key > tk) ? px[j] : 0.f;
                if (key == tk) {
                  int p = atomicAdd(eqcntp, 1);
                  if (p < EQCAP) eqidxp[p] = gm * NNODE + gk + j;
                }
                if (a != 0.f) atomicAdd(&cs[gk + j], a);
                pa[j] = a;
              }
              *(float4*)(Aout + (size_t)gm * NNODE + gk) = av;
            }
          } else {
            float* pv = (float*)&v;
#pragma unroll
            for (int j = 0; j < 4; ++j)
              if (gk + j < K) {
                float xv = A[(size_t)gm * lda + gk + j];
                if (XF) {
                  pv[j] = xfhw(xv, cmul);
                  xfout[(size_t)gm * lda + gk + j] = pv[j];
                } else pv[j] = xv;
                if (MASK) {
                  const unsigned key = tokey(pv[j]);
                  float a = (key > tk) ? pv[j] : 0.f;
                  if (key == tk) {
                    int p = atomicAdd(eqcntp, 1);
                    if (p < EQCAP) eqidxp[p] = gm * NNODE + gk + j;
                  }
                  if (a != 0.f) atomicAdd(&cs[gk + j], a);
                  Aout[(size_t)gm * NNODE + gk + j] = a;
                }
              }
          }
        }
        *(float4*)&As[m][k4] = v;
      }
    } else {
      const int kk = tid >> 4;
      const int m4 = (tid & 15) << 2;
#pragma unroll
      for (int u = 0; u < 4; ++u) {
        const int gk = k0 + kk + (u << 4);
        float4 v = {0.f, 0.f, 0.f, 0.f};
        if (gk < K) {
          const float ds = DSCL ? dsclp[gk] : 1.f;
          if (m0 + m4 + 4 <= M) {
            v = *(const float4*)(A + (size_t)gk * lda + m0 + m4);
            if (DSCL) { v.x *= ds; v.y *= ds; v.z *= ds; v.w *= ds; }
          } else {
            float* pv = (float*)&v;
#pragma unroll
            for (int j = 0; j < 4; ++j)
              if (m0 + m4 + j < M) {
                float t = A[(size_t)gk * lda + m0 + m4 + j];
                pv[j] = DSCL ? t * ds : t;
              }
          }
        }
        As[m4 + 0][kk + (u << 4)] = v.x;
        As[m4 + 1][kk + (u << 4)] = v.y;
        As[m4 + 2][kk + (u << 4)] = v.z;
        As[m4 + 3][kk + (u << 4)] = v.w;
      }
    }
    __syncthreads();

#pragma unroll
    for (int c2 = 0; c2 < 2; ++c2) {
      const int c = (st << 1) + c2;
      s8v bhi[4], blo[4];
#pragma unroll
      for (int nt = 0; nt < 4; ++nt) {
        const int ntg = (wqn << 2) + nt;
        const size_t off = (((size_t)c * 8 + ntg) * 64 + lane) * 8;
        bhi[nt] = *(const s8v*)(Bf + off);
        blo[nt] = *(const s8v*)(Bf + (size_t)kc * 4096 + off);
      }
#pragma unroll
      for (int mt = 0; mt < 2; ++mt) {
        const int row = (wqm << 5) + (mt << 4) + l15;
        const int kof = (c2 << 5) + (quad << 3);
        const f4v a0 = *(const f4v*)&As[row][kof];
        const f4v a1 = *(const f4v*)&As[row][kof + 4];
        s8v ah, al;
#pragma unroll
        for (int j = 0; j < 4; ++j) {
          short h0 = f2bf(a0[j]); ah[j] = h0; al[j] = f2bf(a0[j] - bf2f(h0));
          short h1 = f2bf(a1[j]); ah[j + 4] = h1; al[j + 4] = f2bf(a1[j] - bf2f(h1));
        }
#pragma unroll
        for (int nt = 0; nt < 4; ++nt) {
          acc[mt][nt] = __builtin_amdgcn_mfma_f32_16x16x32_bf16(ah, bhi[nt], acc[mt][nt], 0, 0, 0);
          acc[mt][nt] = __builtin_amdgcn_mfma_f32_16x16x32_bf16(ah, blo[nt], acc[mt][nt], 0, 0, 0);
          acc[mt][nt] = __builtin_amdgcn_mfma_f32_16x16x32_bf16(al, bhi[nt], acc[mt][nt], 0, 0, 0);
        }
      }
    }
  }

  if (MASK) {
    __syncthreads();
    for (int j = tid; j < NNODE; j += 256) {
      const float s = cs[j];
      if (s != 0.f) atomicAdd(&degp[j], s);
    }
  }

  // ---- epilogue ----
  if (TS) {
    for (int nh = 0; nh < 2; ++nh) {
      __syncthreads();
      if (wqn == nh) {
#pragma unroll
        for (int mt = 0; mt < 2; ++mt)
#pragma unroll
          for (int nt = 0; nt < 4; ++nt) {
            const int tn = (nt << 4) + l15;
            const int n  = (wqn << 6) + tn;
            const int mc = (wqm << 5) + (mt << 4) + (quad << 2);
            const f4v a = acc[mt][nt];
#pragma unroll
            for (int reg = 0; reg < 4; ++reg) {
              float v = a[reg];
              if (SCL) v *= scl[m0 + mc + reg];
              if (BIAS) v += bias[n];
              if (RELU) v = fmaxf(v, 0.f);
              As[tn][mc + reg] = v;
            }
          }
      }
      __syncthreads();
      const int row = tid >> 2, cq = tid & 3;
#pragma unroll
      for (int u = 0; u < 4; ++u) {
        const int col = (cq + (u << 2)) << 2;
        if (m0 + col + 4 <= M) {
          const float4 v = *(const float4*)&As[row][col];
          *(float4*)(Cf + (size_t)((nh << 6) + row) * ldc + m0 + col) = v;
        }
      }
    }
    return;
  }

#pragma unroll
  for (int mt = 0; mt < 2; ++mt) {
    const int mb = m0 + (wqm << 5) + (mt << 4) + (quad << 2);
#pragma unroll
    for (int nt = 0; nt < 4; ++nt) {
      const int n = (wqn << 6) + (nt << 4) + l15;
      const f4v a = acc[mt][nt];
      if (!FRAG) {
#pragma unroll
        for (int reg = 0; reg < 4; ++reg) {
          const int m = mb + reg;
          if (m < M) {
            float v = a[reg];
            if (SCL) v *= scl[m];
            if (BIAS) v += bias[n];
            if (RELU) v = fmaxf(v, 0.f);
            Cf[(size_t)m * ldc + n] = v;
          }
        }
      } else {
        s4v h4, l4;
#pragma unroll
        for (int reg = 0; reg < 4; ++reg) {
          const int m = mb + reg;
          float v = (m < M) ? (SCL ? a[reg] * scl[m] : a[reg]) : 0.f;
          short hh = f2bf(v);
          h4[reg] = hh; l4[reg] = f2bf(v - bf2f(hh));
        }
        const int chunkT = mb >> 5, quadT = (mb >> 3) & 3, jT0 = mb & 7;
        const size_t off = (((size_t)chunkT * 8 + (wqn << 2) + nt) * 64
                            + quadT * 16 + l15) * 8 + jT0;
        *(s4v*)(Cfrag + off) = h4;
        *(s4v*)(Cfrag + (size_t)okc * 4096 + off) = l4;
      }
    }
  }
}

// ---------------------------------------------------------------------------
// g4mf v7: proven-best structure (R6/R7): d1-only epilogue, strided o1
// A-loads, packed 2x-u16 12-bit LDS histogram (bits 31..20).
// ---------------------------------------------------------------------------
__global__ void __launch_bounds__(256) g4mf(
    const float* __restrict__ o1,    // [B][128][400] fp32 (out2b)
    const short* __restrict__ wfrag, // dec1_w frags, 2 planes of PLA
    const float* __restrict__ bias,  // dec1_b
    float* __restrict__ xf,          // in-place -> x2
    unsigned* __restrict__ ghist)    // [B][4096]
{
  __shared__ float D2[64][68];       // 17408 B
  __shared__ unsigned hist[2048];    // 4096 bins packed as 2x u16, 8192 B
  const int b = blockIdx.y;
  int p = blockIdx.x, bi = 0;
  while (p >= NT - bi) { p -= NT - bi; ++bi; }
  const int bj = bi + p;
  const int I0 = bi * 64, J0 = bj * 64;
  const bool diag = (bi == bj);

  o1 += (size_t)b * HID * NNODE;
  xf += (size_t)b * NN;
  unsigned* gh = ghist + (size_t)b * 4096;

  const int tid = threadIdx.x;
  const int lane = tid & 63, wave = tid >> 6;
  const int wq = wave & 1;
  const bool d1 = wave < 2;
  const int Bt = (d1 ? bj : bi) * 4;   // B ntile base (global, in wfrag)
  const int quad = lane >> 4, l15 = lane & 15;
  const int M0 = d1 ? I0 : J0;

  for (int i = tid; i < 2048; i += 256) hist[i] = 0u;

  f4v acc[2][4];
#pragma unroll
  for (int i = 0; i < 2; ++i)
#pragma unroll
    for (int j = 0; j < 4; ++j) acc[i][j] = (f4v){0.f, 0.f, 0.f, 0.f};

  const int gm0 = M0 + (wq << 5) + l15;    // mt=0 output row; mt=1 is +16

  for (int c = 0; c < 4; ++c) {
    const int k0 = c << 5;
    s8v bhi[4], blo[4];
#pragma unroll
    for (int nt = 0; nt < 4; ++nt) {
      const int ntg = Bt + nt;
      const size_t off = (((size_t)c * 28 + ntg) * 64 + lane) * 8;
      bhi[nt] = *(const s8v*)(wfrag + off);
      blo[nt] = *(const s8v*)(wfrag + PLA + off);
    }
#pragma unroll
    for (int mt = 0; mt < 2; ++mt) {
      const int gm = gm0 + (mt << 4);
      float av[8];
      if (gm < NNODE) {
        const float* cp = o1 + (size_t)(k0 + (quad << 3)) * NNODE + gm;
#pragma unroll
        for (int j = 0; j < 8; ++j) av[j] = cp[(size_t)j * NNODE];
      } else {
#pragma unroll
        for (int j = 0; j < 8; ++j) av[j] = 0.f;
      }
      s8v ah, al;
#pragma unroll
      for (int j = 0; j < 8; ++j) {
        short h = f2bf(av[j]); ah[j] = h; al[j] = f2bf(av[j] - bf2f(h));
      }
#pragma unroll
      for (int nt = 0; nt < 4; ++nt) {
        acc[mt][nt] = __builtin_amdgcn_mfma_f32_16x16x32_bf16(ah, bhi[nt], acc[mt][nt], 0, 0, 0);
        acc[mt][nt] = __builtin_amdgcn_mfma_f32_16x16x32_bf16(ah, blo[nt], acc[mt][nt], 0, 0, 0);
        acc[mt][nt] = __builtin_amdgcn_mfma_f32_16x16x32_bf16(al, bhi[nt], acc[mt][nt], 0, 0, 0);
      }
    }
  }

  if (!d1) {
#pragma unroll
    for (int mt = 0; mt < 2; ++mt) {
      const int mb = (wq << 5) + (mt << 4) + (quad << 2);
#pragma unroll
      for (int nt = 0; nt < 4; ++nt) {
        const int nn = (nt << 4) + l15;
        const f4v a = acc[mt][nt];
#pragma unroll
        for (int reg = 0; reg < 4; ++reg) D2[mb + reg][nn] = a[reg];
      }
    }
  }
  __syncthreads();

  if (d1) {
    const unsigned w = diag ? 1u : 2u;
#pragma unroll
    for (int mt = 0; mt < 2; ++mt) {
      const int a0 = (wq << 5) + (mt << 4) + (quad << 2);
#pragma unroll
      for (int nt = 0; nt < 4; ++nt) {
        const int nn = (nt << 4) + l15;
        const int gj = J0 + nn;
        const f4v d1v = acc[mt][nt];
        const f4v d2t = *(const f4v*)&D2[nn][a0];
        f4v vv;
#pragma unroll
        for (int reg = 0; reg < 4; ++reg) {
          const int gi = I0 + a0 + reg;
          float v = 0.f;
          if (gi < NNODE && gj < NNODE) {
            v = xf[(size_t)gi * NNODE + gj];
            if (gi != gj)
              v += 0.5f * (d1v[reg] + d2t[reg] + bias[gj] + bias[gi]);
            const unsigned bin = tokey(v) >> 20;
            atomicAdd(&hist[bin >> 1], w << ((bin & 1) << 4));
          }
          vv[reg] = v;
        }
#pragma unroll
        for (int reg = 0; reg < 4; ++reg) {
          const int gi = I0 + a0 + reg;
          if (gi < NNODE && gj < NNODE) xf[(size_t)gi * NNODE + gj] = vv[reg];
        }
        if (!diag && gj < NNODE && (I0 + a0 + 4 <= NNODE)) {
          *(float4*)(xf + (size_t)gj * NNODE + I0 + a0) = *(float4*)&vv;
        }
      }
    }
  }
  __syncthreads();
  for (int i = tid; i < 2048; i += 256) {
    const unsigned v = hist[i];
    const unsigned lo = v & 0xFFFFu, hi = v >> 16;
    if (lo) atomicAdd(&gh[2 * i], lo);
    if (hi) atomicAdd(&gh[2 * i + 1], hi);
  }
}

// ---------------------------------------------------------------------------
__global__ void tzd(const float* __restrict__ x, unsigned* __restrict__ ghist,
                    unsigned* __restrict__ sprefix, int* __restrict__ sk,
                    int* __restrict__ eqcnt, float* __restrict__ deg,
                    float* __restrict__ denom, unsigned* __restrict__ ccnt2) {
  int t = blockIdx.x * 256 + threadIdx.x;
  if (t < BATCH * 4096) ghist[t] = 0u;
  if (t < BATCH) {
    sprefix[t] = 0u; sk[t] = KSEL; eqcnt[t] = 0;
    float v = x[(size_t)t * NN];
    denom[t] = 0.5f * logf((1.0f + v + EPSF) / (1.0f - v + EPSF));
  }
  if (t < BATCH * TSPLIT) ccnt2[t] = 0u;
  if (t < BATCH * NNODE) deg[t] = 0.f;
}

// ---------------------------------------------------------------------------
// thistA: pass A of radix select — bins = bits 19..8 (4096), prefix = top 12.
// Compacts matching keys into this block's PRIVATE segment via an LDS
// counter (no global atomics in the hot loop).
// ---------------------------------------------------------------------------
__global__ void __launch_bounds__(256) thistA(const float* __restrict__ x2,
                                              const unsigned* __restrict__ sprefix,
                                              unsigned* __restrict__ ghist,
                                              unsigned* __restrict__ cand,
                                              unsigned* __restrict__ ccnt2) {
  __shared__ unsigned h[4096];
  __shared__ unsigned lcnt;
  const int b  = blockIdx.y;
  const int sb = blockIdx.x;
  const int tid = threadIdx.x;
  for (int i = tid; i < 4096; i += 256) h[i] = 0u;
  if (tid == 0) lcnt = 0u;
  __syncthreads();

  const unsigned prefix = sprefix[b];
  unsigned* cb = cand + (size_t)b * NN + (size_t)sb * SEG;   // private segment
  const float4* p4 = (const float4*)(x2 + (size_t)b * NN);
  const int i0 = sb * (SEG / 4), i1 = i0 + (SEG / 4);
  for (int i = i0 + tid; i < i1; i += 256) {
    float4 v = p4[i];
    unsigned kk[4] = {tokey(v.x), tokey(v.y), tokey(v.z), tokey(v.w)};
#pragma unroll
    for (int q = 0; q < 4; ++q) {
      const unsigned key = kk[q];
      if ((key & 0xFFF00000u) == prefix) {
        atomicAdd(&h[(key >> 8) & 4095u], 1u);
        const unsigned pos = atomicAdd(&lcnt, 1u);   // LDS atomic: cheap
        cb[pos] = key;
      }
    }
  }
  __syncthreads();
  for (int i = tid; i < 4096; i += 256) {
    unsigned s = h[i];
    if (s) atomicAdd(&ghist[(size_t)b * 4096 + i], s);
  }
  if (tid == 0) ccnt2[b * TSPLIT + sb] = lcnt;       // plain store, no atomic
}

// ---------------------------------------------------------------------------
template<int SH>
__global__ void __launch_bounds__(256) tpick12(unsigned* __restrict__ ghist,
                                               unsigned* __restrict__ sprefix,
                                               int* __restrict__ sk) {
  const int b = blockIdx.x;
  __shared__ unsigned h[4096];
  __shared__ unsigned csum[256];
  unsigned* gh = ghist + (size_t)b * 4096;
  unsigned local = 0;
#pragma unroll
  for (int u = 0; u < 16; ++u) {
    unsigned v = gh[threadIdx.x * 16 + u];
    h[threadIdx.x * 16 + u] = v;
    local += v;
  }
  csum[threadIdx.x] = local;
  __syncthreads();
  if (threadIdx.x == 0) {
    int k = sk[b];
    int bin = 0;
    for (int ch = 255; ch >= 0; --ch) {
      int S = (int)csum[ch];
      if (S >= k) {
        for (int bb = ch * 16 + 15; bb >= ch * 16; --bb) {
          int c = (int)h[bb];
          if (c >= k) { bin = bb; break; }
          k -= c;
        }
        break;
      }
      k -= S;
    }
    sprefix[b] = sprefix[b] | ((unsigned)bin << SH);
    sk[b] = k;
  }
#pragma unroll
  for (int u = 0; u < 16; ++u) gh[threadIdx.x * 16 + u] = 0u;
}

// ---------------------------------------------------------------------------
// thistC: final 8-bit pass over the 8 per-block candidate segments; picks
// tau/rrem directly.
// ---------------------------------------------------------------------------
__global__ void __launch_bounds__(256) thistC(const unsigned* __restrict__ cand,
                                              const unsigned* __restrict__ ccnt2,
                                              const unsigned* __restrict__ sprefix,
                                              const int* __restrict__ sk,
                                              unsigned* __restrict__ tau,
                                              int* __restrict__ rrem) {
  __shared__ unsigned h[8][256];
  const int b = blockIdx.x;
  const int tid = threadIdx.x;
  for (int i = tid; i < 8 * 256; i += 256) ((unsigned*)h)[i] = 0u;
  __syncthreads();
  const unsigned prefix = sprefix[b];           // top 24 bits set
  const int rep = tid & 7;
  for (int sb = 0; sb < TSPLIT; ++sb) {
    const unsigned n = ccnt2[b * TSPLIT + sb];
    const unsigned* cp = cand + (size_t)b * NN + (size_t)sb * SEG;
    for (unsigned i = tid; i < n; i += 256) {
      const unsigned key = cp[i];
      if ((key & 0xFFFFFF00u) == prefix) atomicAdd(&h[rep][key & 255u], 1u);
    }
  }
  __syncthreads();
  if (tid < 256) {
    const unsigned s = h[0][tid] + h[1][tid] + h[2][tid] + h[3][tid]
                     + h[4][tid] + h[5][tid] + h[6][tid] + h[7][tid];
    h[0][tid] = s;
  }
  __syncthreads();
  if (tid == 0) {
    int k = sk[b];
    unsigned byte = 0u;
    for (int bin = 255; bin >= 0; --bin) {
      int c = (int)h[0][bin];
      if (c >= k) { byte = (unsigned)bin; break; }
      k -= c;
    }
    tau[b] = prefix | byte;
    rrem[b] = k;
  }
}

// ---------------------------------------------------------------------------
// eqdinv: fused tie-fix + diag-fill + dinv, one block per sample.
// ---------------------------------------------------------------------------
__global__ void __launch_bounds__(256) eqdinv(
    float* __restrict__ A, const float* __restrict__ x2,
    float* __restrict__ deg, float* __restrict__ dinv,
    const int* __restrict__ eqcnt, const int* __restrict__ eqidx,
    const int* __restrict__ rrem) {
  const int b = blockIdx.x;
  int cnt = eqcnt[b]; if (cnt > EQCAP) cnt = EQCAP;
  const int r = rrem[b];
  for (int t = threadIdx.x; t < cnt; t += 256) {
    int idx = eqidx[b * EQCAP + t];
    int rank = 0;
    for (int u = 0; u < cnt; ++u) rank += (eqidx[b * EQCAP + u] < idx) ? 1 : 0;
    if (rank < r) {
      float v = x2[(size_t)b * NN + idx];
      A[(size_t)b * NN + idx] = v;
      atomicAdd(&deg[b * NNODE + idx % NNODE], v);
    }
  }
  __syncthreads();
  for (int j = threadIdx.x; j < NNODE; j += 256) {
    float d = deg[b * NNODE + j];
    size_t o = (size_t)b * NN + (size_t)j * NNODE + j;
    if (A[o] == 0.f) { A[o] = 1.0f; d += 1.0f; }
    dinv[b * NNODE + j] = (d == 0.f) ? 0.f : 1.0f / sqrtf(d);
  }
}

__global__ void head_k(const float* __restrict__ h2, const float* __restrict__ fc_w,
                       const float* __restrict__ fc_b, float* __restrict__ out) {
  int b = blockIdx.x;
  int f = threadIdx.x;
  float s = 0.f;
  const float* p = h2 + (size_t)b * NNODE * HID + f;
  for (int j = 0; j < NNODE; ++j) s += p[(size_t)j * HID];
  float pv = fmaxf(s / (float)NNODE, 0.f);
  __shared__ float r0[128], r1[128];
  r0[f] = pv * fc_w[f * 2 + 0];
  r1[f] = pv * fc_w[f * 2 + 1];
  __syncthreads();
  for (int sft = 64; sft > 0; sft >>= 1) {
    if (f < sft) { r0[f] += r0[f + sft]; r1[f] += r1[f + sft]; }
    __syncthreads();
  }
  if (f == 0) {
    out[b * 2 + 0] = r0[0] + fc_b[0];
    out[b * 2 + 1] = r1[0] + fc_b[1];
  }
}

// ---------------------------------------------------------------------------
extern "C" void kernel_launch(void* const* d_in, const int* in_sizes, int n_in,
                              void* d_out, int out_size, void* d_ws, size_t ws_size,
                              hipStream_t stream) {
  const float* x      = (const float*)d_in[0];
  const float* enc1_w = (const float*)d_in[2];
  const float* enc1_b = (const float*)d_in[3];
  const float* enc2_w = (const float*)d_in[4];
  const float* enc2_b = (const float*)d_in[5];
  const float* dec2_w = (const float*)d_in[6];
  const float* dec2_b = (const float*)d_in[7];
  const float* dec1_w = (const float*)d_in[8];
  const float* dec1_b = (const float*)d_in[9];
  const float* gcn1_w = (const float*)d_in[10];
  const float* gcn1_b = (const float*)d_in[11];
  const float* gcn2_w = (const float*)d_in[12];
  const float* gcn2_b = (const float*)d_in[13];
  const float* fc_w   = (const float*)d_in[14];
  const float* fc_b   = (const float*)d_in[15];
  float* out = (float*)d_out;
  (void)in_sizes; (void)n_in; (void)out_size; (void)ws_size;

  float* ws = (float*)d_ws;
  size_t off = 0;
  auto take = [&](size_t n) { float* p = ws + off; off += (n + 63) & ~(size_t)63; return p; };
  float* xf   = take((size_t)BATCH * NN);          // xf -> x2 (in place)
  float* dl   = take((size_t)BATCH * NN);          // cand keys (radix), then A (sparsified)
  float* o1   = take((size_t)BATCH * HID * NNODE); // out1 -> out2b; later xwfrag alias
  float* o2   = take((size_t)BATCH * HID * HID);
  float* hbuf = take((size_t)BATCH * NNODE * HID); // h -> h2
  float* denom = take(BATCH);
  float* dinv  = take((size_t)BATCH * NNODE);
  float* deg   = take((size_t)BATCH * NNODE);
  unsigned* tau = (unsigned*)take(BATCH);
  int* rrem  = (int*)take(BATCH);
  int* eqcnt = (int*)take(BATCH);
  int* eqidx = (int*)take((size_t)BATCH * EQCAP);
  unsigned* ghist   = (unsigned*)take((size_t)BATCH * 4096);   // 12-bit bins
  unsigned* sprefix = (unsigned*)take(BATCH);
  int*      sk      = (int*)take(BATCH);
  unsigned* ccnt2   = (unsigned*)take((size_t)BATCH * TSPLIT); // per-(b,sb) counts
  short* w1frag = (short*)take((size_t)FRAGS + 64);          // gcn1_w, 2 planes K448
  short* w2frag = (short*)take((size_t)4 * 4096 + 64);       // gcn2_w, 2 planes K128
  short* e1frag = (short*)take((size_t)FRAGS + 64);          // enc1_w
  short* e2frag = (short*)take((size_t)FRAGS + 64);          // enc2_w
  short* dfrag  = (short*)take((size_t)PLA + 64);            // dec1_w (2*PLA shorts)
  short* xwfrag = (short*)o1;          // aliases dead o1 (post-g4mf)
  unsigned* cand = (unsigned*)dl;      // candidate keys, dead before the MASK kernel
  const long sXW = 2L * FRAGS;

  tzd<<<2048, 256, 0, stream>>>(x, ghist, sprefix, sk, eqcnt, deg, denom, ccnt2);
  bsplit5<<<dim3(224, 5), 256, 0, stream>>>(gcn1_w, gcn2_w, enc1_w, enc2_w, dec1_w,
                                            w1frag, w2frag, e1frag, e2frag, dfrag);

  // G1 (+fused xf): reads raw x, computes/stores xf, o1 = (relu(xf@enc1_w+b))^T
  mfgemm<false, false, true, true, false, true, true, false, false><<<dim3(7, BATCH), 256, 0, stream>>>(
      x, NN, NNODE, e1frag, 0, KC400, enc1_b, nullptr,
      o1, (long)HID * NNODE, NNODE, nullptr, 0, 0, denom, xf,
      nullptr, nullptr, nullptr, nullptr, nullptr, nullptr, NNODE, NNODE);
  // G2: o2 = relu(o1 @ enc2_w + b)
  mfgemm<false, false, true, true, false, false, false, false, false><<<dim3(2, BATCH), 256, 0, stream>>>(
      o1, (long)HID * NNODE, NNODE, e2frag, 0, KC400, enc2_b, nullptr,
      o2, (long)HID * HID, HID, nullptr, 0, 0, nullptr, nullptr,
      nullptr, nullptr, nullptr, nullptr, nullptr, nullptr, HID, NNODE);
  // G3: out2b = relu(o2 @ dec2_w + b + o1), in-place (fp32)
  gemm64<false, true, true, true, false><<<dim3(7, 2, BATCH), 256, 0, stream>>>(
      o2, (long)HID * HID, HID, dec2_w, 0, NNODE, dec2_b,
      o1, (long)HID * NNODE, o1, (long)HID * NNODE, NNODE, HID, NNODE, HID);

  // fused delta + symmetrize + x2 + pass-0 12-bit histogram (packed LDS)
  g4mf<<<dim3(NT * (NT + 1) / 2, BATCH), 256, 0, stream>>>(o1, dfrag, dec1_b, xf, ghist);

  // radix select: 12 + 12 + 8 bits; final pass on compact candidate lists
  tpick12<20><<<BATCH, 256, 0, stream>>>(ghist, sprefix, sk);
  thistA<<<dim3(TSPLIT, BATCH), 256, 0, stream>>>(xf, sprefix, ghist, cand, ccnt2);
  tpick12<8><<<BATCH, 256, 0, stream>>>(ghist, sprefix, sk);
  thistC<<<BATCH, 256, 0, stream>>>(cand, ccnt2, sprefix, sk, tau, rrem);

  // GCN1-frag (UNscaled xw = x2@w1) + fused build_kc (A/deg/ties) — MASK=true.
  // (overwrites cand/dl with A; cand fully consumed by thistC above)
  mfgemm<false, true, false, false, false, false, false, true, false><<<dim3(7, BATCH), 256, 0, stream>>>(
      xf, NN, NNODE, w1frag, 0, KC400, nullptr, nullptr,
      nullptr, 0, 128, xwfrag, sXW, KC400, nullptr, nullptr,
      tau, dl, deg, eqcnt, eqidx, nullptr, NNODE, NNODE);
  // tie-fix + diag-fill + dinv
  eqdinv<<<BATCH, 256, 0, stream>>>(dl, xf, deg, dinv, eqcnt, eqidx, rrem);

  // AT-gather 1: h = relu(dinv[j] * sum_i (A[i,j]*dinv[i]) * xw[i,f] + b1)
  mfgemm<true, false, true, true, true, false, false, false, true><<<dim3(7, BATCH), 256, 0, stream>>>(
      dl, NN, NNODE, xwfrag, sXW, KC400, gcn1_b, dinv,
      hbuf, (long)NNODE * HID, HID, nullptr, 0, 0, nullptr, nullptr,
      nullptr, nullptr, nullptr, nullptr, nullptr, dinv, NNODE, NNODE);
  // GCN2-frag (UNscaled h@w2)
  mfgemm<false, true, false, false, false, false, false, false, false><<<dim3(7, BATCH), 256, 0, stream>>>(
      hbuf, (long)NNODE * HID, HID, w2frag, 0, 4, nullptr, nullptr,
      nullptr, 0, 128, xwfrag, sXW, KC400, nullptr, nullptr,
      nullptr, nullptr, nullptr, nullptr, nullptr, nullptr, NNODE, HID);
  // AT-gather 2: h2 = dinv[j] * sum_i (A[i,j]*dinv[i]) * hw[i,f] + b2
  mfgemm<true, false, true, false, true, false, false, false, true><<<dim3(7, BATCH), 256, 0, stream>>>(
      dl, NN, NNODE, xwfrag, sXW, KC400, gcn2_b, dinv,
      hbuf, (long)NNODE * HID, HID, nullptr, 0, 0, nullptr, nullptr,
      nullptr, nullptr, nullptr, nullptr, nullptr, dinv, NNODE, NNODE);

  head_k<<<BATCH, HID, 0, stream>>>(hbuf, fc_w, fc_b, out);
}

// Round 11
// 622.290 us; speedup vs baseline: 1.9958x; 1.0203x over previous
//
#include <hip/hip_runtime.h>
#include <hip/hip_bf16.h>
#include <math.h>

#define BATCH 128
#define NNODE 400
#define HID   128
#define NN    (NNODE*NNODE)      // 160000
#define KSEL  32000              // int(NN*0.2)
#define EQCAP 1024
#define EPSF  1e-9f
#define TSPLIT 8
#define SEG   (NN / TSPLIT)      // 20000
#define NT    7                  // ceil(400/64)
#define KC400 14                 // 448/32
#define FRAGS (KC400*4096)       // shorts per plane, K=400pad, N=128
#define PLA   57344              // shorts per plane: 4 kchunks * 28 ntiles * 512 (dec1_w: K=128, N=448pad)

// map float -> unsigned so that descending float order == descending unsigned order
__device__ __forceinline__ unsigned tokey(float f) {
  unsigned u = __float_as_uint(f);
  return (u & 0x80000000u) ? ~u : (u | 0x80000000u);
}

// fp32 -> bf16 (RNE) and back, as raw shorts
__device__ __forceinline__ short f2bf(float f) {
  unsigned u = __float_as_uint(f);
  u += 0x7fffu + ((u >> 16) & 1u);
  return (short)(u >> 16);
}
__device__ __forceinline__ float bf2f(short s) {
  return __uint_as_float(((unsigned)(unsigned short)s) << 16);
}

// fisher transform via hw log2: 0.5*ln((1+x+e)/(1-x+e))/dnm == (log2(a)-log2(b))*cmul
__device__ __forceinline__ float xfhw(float xv, float cmul) {
  float la = __builtin_amdgcn_logf(1.0f + xv + EPSF);
  float lb = __builtin_amdgcn_logf(1.0f - xv + EPSF);
  return (la - lb) * cmul;
}

typedef __attribute__((ext_vector_type(8))) short s8v;
typedef __attribute__((ext_vector_type(4))) short s4v;
typedef __attribute__((ext_vector_type(4))) float f4v;

// ---------------------------------------------------------------------------
// 64x64-tile fp32 GEMM (VALU) — only G3 (residual, in-place) still uses this.
// ---------------------------------------------------------------------------
#define BK 16
#define LP 68

template<bool AT, bool BIAS, bool RES, bool RELU, bool TS>
__global__ void __launch_bounds__(256) gemm64(
    const float* __restrict__ A, long sA, int lda,
    const float* __restrict__ B, long sB, int ldb,
    const float* __restrict__ bias,
    const float* __restrict__ Res, long sRes,
    float* __restrict__ C, long sC, int ldc,
    int M, int Nc, int K)
{
  __shared__ float As[BK][LP];
  __shared__ float Bs[BK][LP];
  const int bz = blockIdx.z;
  A += (size_t)bz * sA;
  B += (size_t)bz * sB;
  C += (size_t)bz * sC;
  const float* Rp = RES ? (Res + (size_t)bz * sRes) : nullptr;

  const int n0 = blockIdx.x * 64;
  const int m0 = blockIdx.y * 64;
  const int tid = threadIdx.x;
  const int tx = tid & 15, ty = tid >> 4;
  const bool edgeM = (m0 + 64 > M);
  const bool edgeN = (n0 + 64 > Nc);

  float acc[4][4];
#pragma unroll
  for (int i = 0; i < 4; ++i)
#pragma unroll
    for (int j = 0; j < 4; ++j) acc[i][j] = 0.f;

  for (int k0 = 0; k0 < K; k0 += BK) {
    if (!AT) {
      const int m = tid & 63, g = tid >> 6;
      if (!edgeM) {
        const float4 v = *(const float4*)(A + (size_t)(m0 + m) * lda + k0 + 4 * g);
        As[4 * g + 0][m] = v.x; As[4 * g + 1][m] = v.y;
        As[4 * g + 2][m] = v.z; As[4 * g + 3][m] = v.w;
      } else {
        const int gm = m0 + m;
        const bool ok = gm < M;
#pragma unroll
        for (int j = 0; j < 4; ++j)
          As[4 * g + j][m] = ok ? A[(size_t)gm * lda + k0 + 4 * g + j] : 0.f;
      }
    } else {
      const int k = tid >> 4, mg = tid & 15;
      if (!edgeM) {
        const float4 v = *(const float4*)(A + (size_t)(k0 + k) * lda + m0 + 4 * mg);
        *(float4*)&As[k][4 * mg] = v;
      } else {
#pragma unroll
        for (int j = 0; j < 4; ++j) {
          const int gm = m0 + 4 * mg + j;
          As[k][4 * mg + j] = (gm < M) ? A[(size_t)(k0 + k) * lda + gm] : 0.f;
        }
      }
    }
    {
      const int k = tid >> 4, ng = tid & 15;
      if (!edgeN) {
        const float4 v = *(const float4*)(B + (size_t)(k0 + k) * ldb + n0 + 4 * ng);
        *(float4*)&Bs[k][4 * ng] = v;
      } else {
#pragma unroll
        for (int j = 0; j < 4; ++j) {
          const int gn = n0 + 4 * ng + j;
          Bs[k][4 * ng + j] = (gn < Nc) ? B[(size_t)(k0 + k) * ldb + gn] : 0.f;
        }
      }
    }
    __syncthreads();
#pragma unroll
    for (int kk = 0; kk < BK; ++kk) {
      const float4 a = *(const float4*)&As[kk][ty << 2];
      const float4 b = *(const float4*)&Bs[kk][tx << 2];
      const float av[4] = {a.x, a.y, a.z, a.w};
      const float bv[4] = {b.x, b.y, b.z, b.w};
#pragma unroll
      for (int i = 0; i < 4; ++i)
#pragma unroll
        for (int j = 0; j < 4; ++j) acc[i][j] += av[i] * bv[j];
    }
    __syncthreads();
  }

#pragma unroll
  for (int i = 0; i < 4; ++i) {
    const int m = m0 + (ty << 2) + i;
    if (m >= M) continue;
#pragma unroll
    for (int j = 0; j < 4; ++j) {
      const int n = n0 + (tx << 2) + j;
      if (n >= Nc) continue;
      float v = acc[i][j];
      if (BIAS) v += bias[n];
      const size_t loc = TS ? ((size_t)n * ldc + m) : ((size_t)m * ldc + n);
      if (RES) v += Rp[loc];
      if (RELU) v = fmaxf(v, 0.f);
      C[loc] = v;
    }
  }
}

// ---------------------------------------------------------------------------
// bsplit5: all 5 weight-fragment builds in ONE launch (blockIdx.y selects).
// ---------------------------------------------------------------------------
__global__ void bsplit5(
    const float* __restrict__ gcn1_w, const float* __restrict__ gcn2_w,
    const float* __restrict__ enc1_w, const float* __restrict__ enc2_w,
    const float* __restrict__ dec1_w,
    short* __restrict__ w1frag, short* __restrict__ w2frag,
    short* __restrict__ e1frag, short* __restrict__ e2frag,
    short* __restrict__ dfrag) {
  const float* W; short* out; int K, Kpad, N, Npad;
  switch (blockIdx.y) {
    case 0: W = gcn1_w; out = w1frag; K = NNODE; Kpad = 448; N = HID;   Npad = 128; break;
    case 1: W = gcn2_w; out = w2frag; K = HID;   Kpad = 128; N = HID;   Npad = 128; break;
    case 2: W = enc1_w; out = e1frag; K = NNODE; Kpad = 448; N = HID;   Npad = 128; break;
    case 3: W = enc2_w; out = e2frag; K = NNODE; Kpad = 448; N = HID;   Npad = 128; break;
    default: W = dec1_w; out = dfrag; K = HID;   Kpad = 128; N = NNODE; Npad = 448; break;
  }
  int t = blockIdx.x * 256 + threadIdx.x;
  if (t >= Kpad * Npad) return;
  int k = t / Npad, n = t - k * Npad;
  float v = (k < K && n < N) ? W[(size_t)k * N + n] : 0.f;
  short hi = f2bf(v);
  short lo = f2bf(v - bf2f(hi));
  int ntiles = Npad >> 4;
  size_t idx = (((size_t)(k >> 5) * ntiles + (n >> 4)) * 64
                + (((k >> 3) & 3) * 16 + (n & 15))) * 8 + (k & 7);
  size_t PL = (size_t)(Kpad >> 5) * ntiles * 512;
  out[idx] = hi;
  out[PL + idx] = lo;
}

// ---------------------------------------------------------------------------
// MFMA GEMM (bf16 split-3), N fixed 128.
// AT: A[m][k]=Araw[k*lda+m].  FRAG: emit frag-ordered bf16 hi/lo (next B).
// TS: store transposed C^T[n][m] via LDS.  XF: fisher transform fused (G1).
// MASK (!AT only): while staging x2, ALSO write A=mask(x2,tau) to Aout,
//   gather ties, accumulate per-column sums -> deg (fused build_kc).
// DSCL (AT only): multiply the staged A element by dsclp[gk].
// POOL (!TS,!FRAG): skip the C store; accumulate per-column sums of the
//   (scl/bias-applied) output tile into poolp[b][128] — fuses the head's
//   node-mean so h2 never materializes.
// ---------------------------------------------------------------------------
template<bool AT, bool FRAG, bool BIAS, bool RELU, bool SCL, bool TS, bool XF,
         bool MASK, bool DSCL, bool POOL>
__global__ void __launch_bounds__(256) mfgemm(
    const float* __restrict__ A, long sA, int lda,
    const short* __restrict__ Bf, long sB, int kc,
    const float* __restrict__ bias,
    const float* __restrict__ scl,
    float* __restrict__ Cf, long sCf, int ldc,
    short* __restrict__ Cfrag, long sCfrag, int okc,
    const float* __restrict__ denomp, float* __restrict__ xfout,
    const unsigned* __restrict__ taup, float* __restrict__ Aout,
    float* __restrict__ degp, int* __restrict__ eqcntp,
    int* __restrict__ eqidxp, const float* __restrict__ dsclp,
    float* __restrict__ poolp,
    int M, int K)
{
  __shared__ float As[64][68];
  __shared__ float cs[MASK ? NNODE : 1];
  __shared__ float ps[POOL ? HID : 1];
  const int bz = blockIdx.y;
  A += (size_t)bz * sA;
  Bf += (size_t)bz * sB;
  if (SCL) scl += (size_t)bz * NNODE;
  if (!FRAG) Cf += (size_t)bz * sCf;
  else       Cfrag += (size_t)bz * sCfrag;
  if (XF) xfout += (size_t)bz * sA;
  const float cmul = XF ? (0.34657359027997264f / denomp[bz]) : 0.f;
  const unsigned tk = MASK ? taup[bz] : 0u;
  if (MASK) { Aout += (size_t)bz * NN; degp += (size_t)bz * NNODE;
              eqcntp += bz; eqidxp += (size_t)bz * EQCAP; }
  if (DSCL) dsclp += (size_t)bz * NNODE;
  if (POOL) poolp += (size_t)bz * HID;

  const int tid = threadIdx.x;
  const int lane = tid & 63, wave = tid >> 6;
  const int wqm = wave >> 1, wqn = wave & 1;
  const int quad = lane >> 4, l15 = lane & 15;
  const int m0 = blockIdx.x * 64;

  if (MASK) {
    for (int i = tid; i < NNODE; i += 256) cs[i] = 0.f;
    __syncthreads();
  }
  if (POOL) {
    for (int i = tid; i < HID; i += 256) ps[i] = 0.f;
  }

  f4v acc[2][4];
#pragma unroll
  for (int i = 0; i < 2; ++i)
#pragma unroll
    for (int j = 0; j < 4; ++j) acc[i][j] = (f4v){0.f, 0.f, 0.f, 0.f};

  const int nstage = (K + 63) >> 6;
  for (int st = 0; st < nstage; ++st) {
    const int k0 = st << 6;
    if (st) __syncthreads();
    if (!AT) {
      const int mrow = tid >> 4;
      const int k4 = (tid & 15) << 2;
#pragma unroll
      for (int u = 0; u < 4; ++u) {
        const int m = mrow + (u << 4);
        const int gm = m0 + m, gk = k0 + k4;
        float4 v = {0.f, 0.f, 0.f, 0.f};
        if (gm < M) {
          if (gk + 4 <= K) {
            float4 xv = *(const float4*)(A + (size_t)gm * lda + gk);
            if (XF) {
              v.x = xfhw(xv.x, cmul);
              v.y = xfhw(xv.y, cmul);
              v.z = xfhw(xv.z, cmul);
              v.w = xfhw(xv.w, cmul);
              *(float4*)(xfout + (size_t)gm * lda + gk) = v;
            } else v = xv;
            if (MASK) {
              float4 av;
              float* pa = (float*)&av;
              const float* px = (const float*)&v;
#pragma unroll
              for (int j = 0; j < 4; ++j) {
                const unsigned key = tokey(px[j]);
                float a = (key > tk) ? px[j] : 0.f;
                if (key == tk) {
                  int p = atomicAdd(eqcntp, 1);
                  if (p < EQCAP) eqidxp[p] = gm * NNODE + gk + j;
                }
                if (a != 0.f) atomicAdd(&cs[gk + j], a);
                pa[j] = a;
              }
              *(float4*)(Aout + (size_t)gm * NNODE + gk) = av;
            }
          } else {
            float* pv = (float*)&v;
#pragma unroll
            for (int j = 0; j < 4; ++j)
              if (gk + j < K) {
                float xv = A[(size_t)gm * lda + gk + j];
                if (XF) {
                  pv[j] = xfhw(xv, cmul);
                  xfout[(size_t)gm * lda + gk + j] = pv[j];
                } else pv[j] = xv;
                if (MASK) {
                  const unsigned key = tokey(pv[j]);
                  float a = (key > tk) ? pv[j] : 0.f;
                  if (key == tk) {
                    int p = atomicAdd(eqcntp, 1);
                    if (p < EQCAP) eqidxp[p] = gm * NNODE + gk + j;
                  }
                  if (a != 0.f) atomicAdd(&cs[gk + j], a);
                  Aout[(size_t)gm * NNODE + gk + j] = a;
                }
              }
          }
        }
        *(float4*)&As[m][k4] = v;
      }
    } else {
      const int kk = tid >> 4;
      const int m4 = (tid & 15) << 2;
#pragma unroll
      for (int u = 0; u < 4; ++u) {
        const int gk = k0 + kk + (u << 4);
        float4 v = {0.f, 0.f, 0.f, 0.f};
        if (gk < K) {
          const float ds = DSCL ? dsclp[gk] : 1.f;
          if (m0 + m4 + 4 <= M) {
            v = *(const float4*)(A + (size_t)gk * lda + m0 + m4);
            if (DSCL) { v.x *= ds; v.y *= ds; v.z *= ds; v.w *= ds; }
          } else {
            float* pv = (float*)&v;
#pragma unroll
            for (int j = 0; j < 4; ++j)
              if (m0 + m4 + j < M) {
                float t = A[(size_t)gk * lda + m0 + m4 + j];
                pv[j] = DSCL ? t * ds : t;
              }
          }
        }
        As[m4 + 0][kk + (u << 4)] = v.x;
        As[m4 + 1][kk + (u << 4)] = v.y;
        As[m4 + 2][kk + (u << 4)] = v.z;
        As[m4 + 3][kk + (u << 4)] = v.w;
      }
    }
    __syncthreads();

#pragma unroll
    for (int c2 = 0; c2 < 2; ++c2) {
      const int c = (st << 1) + c2;
      s8v bhi[4], blo[4];
#pragma unroll
      for (int nt = 0; nt < 4; ++nt) {
        const int ntg = (wqn << 2) + nt;
        const size_t off = (((size_t)c * 8 + ntg) * 64 + lane) * 8;
        bhi[nt] = *(const s8v*)(Bf + off);
        blo[nt] = *(const s8v*)(Bf + (size_t)kc * 4096 + off);
      }
#pragma unroll
      for (int mt = 0; mt < 2; ++mt) {
        const int row = (wqm << 5) + (mt << 4) + l15;
        const int kof = (c2 << 5) + (quad << 3);
        const f4v a0 = *(const f4v*)&As[row][kof];
        const f4v a1 = *(const f4v*)&As[row][kof + 4];
        s8v ah, al;
#pragma unroll
        for (int j = 0; j < 4; ++j) {
          short h0 = f2bf(a0[j]); ah[j] = h0; al[j] = f2bf(a0[j] - bf2f(h0));
          short h1 = f2bf(a1[j]); ah[j + 4] = h1; al[j + 4] = f2bf(a1[j] - bf2f(h1));
        }
#pragma unroll
        for (int nt = 0; nt < 4; ++nt) {
          acc[mt][nt] = __builtin_amdgcn_mfma_f32_16x16x32_bf16(ah, bhi[nt], acc[mt][nt], 0, 0, 0);
          acc[mt][nt] = __builtin_amdgcn_mfma_f32_16x16x32_bf16(ah, blo[nt], acc[mt][nt], 0, 0, 0);
          acc[mt][nt] = __builtin_amdgcn_mfma_f32_16x16x32_bf16(al, bhi[nt], acc[mt][nt], 0, 0, 0);
        }
      }
    }
  }

  if (MASK) {
    __syncthreads();
    for (int j = tid; j < NNODE; j += 256) {
      const float s = cs[j];
      if (s != 0.f) atomicAdd(&degp[j], s);
    }
  }

  // ---- epilogue ----
  if (POOL) {
    __syncthreads();   // ps init visible; As no longer needed
#pragma unroll
    for (int nt = 0; nt < 4; ++nt) {
      const int n = (wqn << 6) + (nt << 4) + l15;
      float s = 0.f;
#pragma unroll
      for (int mt = 0; mt < 2; ++mt) {
        const int mb = m0 + (wqm << 5) + (mt << 4) + (quad << 2);
        const f4v a = acc[mt][nt];
#pragma unroll
        for (int reg = 0; reg < 4; ++reg) {
          const int m = mb + reg;
          if (m < M) {
            float v = a[reg];
            if (SCL) v *= scl[m];
            if (BIAS) v += bias[n];
            s += v;
          }
        }
      }
      atomicAdd(&ps[n], s);
    }
    __syncthreads();
    for (int i = tid; i < HID; i += 256) {
      const float s = ps[i];
      if (s != 0.f) atomicAdd(&poolp[i], s);
    }
    return;
  }

  if (TS) {
    for (int nh = 0; nh < 2; ++nh) {
      __syncthreads();
      if (wqn == nh) {
#pragma unroll
        for (int mt = 0; mt < 2; ++mt)
#pragma unroll
          for (int nt = 0; nt < 4; ++nt) {
            const int tn = (nt << 4) + l15;
            const int n  = (wqn << 6) + tn;
            const int mc = (wqm << 5) + (mt << 4) + (quad << 2);
            const f4v a = acc[mt][nt];
#pragma unroll
            for (int reg = 0; reg < 4; ++reg) {
              float v = a[reg];
              if (SCL) v *= scl[m0 + mc + reg];
              if (BIAS) v += bias[n];
              if (RELU) v = fmaxf(v, 0.f);
              As[tn][mc + reg] = v;
            }
          }
      }
      __syncthreads();
      const int row = tid >> 2, cq = tid & 3;
#pragma unroll
      for (int u = 0; u < 4; ++u) {
        const int col = (cq + (u << 2)) << 2;
        if (m0 + col + 4 <= M) {
          const float4 v = *(const float4*)&As[row][col];
          *(float4*)(Cf + (size_t)((nh << 6) + row) * ldc + m0 + col) = v;
        }
      }
    }
    return;
  }

#pragma unroll
  for (int mt = 0; mt < 2; ++mt) {
    const int mb = m0 + (wqm << 5) + (mt << 4) + (quad << 2);
#pragma unroll
    for (int nt = 0; nt < 4; ++nt) {
      const int n = (wqn << 6) + (nt << 4) + l15;
      const f4v a = acc[mt][nt];
      if (!FRAG) {
#pragma unroll
        for (int reg = 0; reg < 4; ++reg) {
          const int m = mb + reg;
          if (m < M) {
            float v = a[reg];
            if (SCL) v *= scl[m];
            if (BIAS) v += bias[n];
            if (RELU) v = fmaxf(v, 0.f);
            Cf[(size_t)m * ldc + n] = v;
          }
        }
      } else {
        s4v h4, l4;
#pragma unroll
        for (int reg = 0; reg < 4; ++reg) {
          const int m = mb + reg;
          float v = (m < M) ? (SCL ? a[reg] * scl[m] : a[reg]) : 0.f;
          short hh = f2bf(v);
          h4[reg] = hh; l4[reg] = f2bf(v - bf2f(hh));
        }
        const int chunkT = mb >> 5, quadT = (mb >> 3) & 3, jT0 = mb & 7;
        const size_t off = (((size_t)chunkT * 8 + (wqn << 2) + nt) * 64
                            + quadT * 16 + l15) * 8 + jT0;
        *(s4v*)(Cfrag + off) = h4;
        *(s4v*)(Cfrag + (size_t)okc * 4096 + off) = l4;
      }
    }
  }
}

// ---------------------------------------------------------------------------
// g4mf v7: proven-best structure (R6/R7): d1-only epilogue, strided o1
// A-loads, packed 2x-u16 12-bit LDS histogram (bits 31..20).
// ---------------------------------------------------------------------------
__global__ void __launch_bounds__(256) g4mf(
    const float* __restrict__ o1,    // [B][128][400] fp32 (out2b)
    const short* __restrict__ wfrag, // dec1_w frags, 2 planes of PLA
    const float* __restrict__ bias,  // dec1_b
    float* __restrict__ xf,          // in-place -> x2
    unsigned* __restrict__ ghist)    // [B][4096]
{
  __shared__ float D2[64][68];       // 17408 B
  __shared__ unsigned hist[2048];    // 4096 bins packed as 2x u16, 8192 B
  const int b = blockIdx.y;
  int p = blockIdx.x, bi = 0;
  while (p >= NT - bi) { p -= NT - bi; ++bi; }
  const int bj = bi + p;
  const int I0 = bi * 64, J0 = bj * 64;
  const bool diag = (bi == bj);

  o1 += (size_t)b * HID * NNODE;
  xf += (size_t)b * NN;
  unsigned* gh = ghist + (size_t)b * 4096;

  const int tid = threadIdx.x;
  const int lane = tid & 63, wave = tid >> 6;
  const int wq = wave & 1;
  const bool d1 = wave < 2;
  const int Bt = (d1 ? bj : bi) * 4;   // B ntile base (global, in wfrag)
  const int quad = lane >> 4, l15 = lane & 15;
  const int M0 = d1 ? I0 : J0;

  for (int i = tid; i < 2048; i += 256) hist[i] = 0u;

  f4v acc[2][4];
#pragma unroll
  for (int i = 0; i < 2; ++i)
#pragma unroll
    for (int j = 0; j < 4; ++j) acc[i][j] = (f4v){0.f, 0.f, 0.f, 0.f};

  const int gm0 = M0 + (wq << 5) + l15;    // mt=0 output row; mt=1 is +16

  for (int c = 0; c < 4; ++c) {
    const int k0 = c << 5;
    s8v bhi[4], blo[4];
#pragma unroll
    for (int nt = 0; nt < 4; ++nt) {
      const int ntg = Bt + nt;
      const size_t off = (((size_t)c * 28 + ntg) * 64 + lane) * 8;
      bhi[nt] = *(const s8v*)(wfrag + off);
      blo[nt] = *(const s8v*)(wfrag + PLA + off);
    }
#pragma unroll
    for (int mt = 0; mt < 2; ++mt) {
      const int gm = gm0 + (mt << 4);
      float av[8];
      if (gm < NNODE) {
        const float* cp = o1 + (size_t)(k0 + (quad << 3)) * NNODE + gm;
#pragma unroll
        for (int j = 0; j < 8; ++j) av[j] = cp[(size_t)j * NNODE];
      } else {
#pragma unroll
        for (int j = 0; j < 8; ++j) av[j] = 0.f;
      }
      s8v ah, al;
#pragma unroll
      for (int j = 0; j < 8; ++j) {
        short h = f2bf(av[j]); ah[j] = h; al[j] = f2bf(av[j] - bf2f(h));
      }
#pragma unroll
      for (int nt = 0; nt < 4; ++nt) {
        acc[mt][nt] = __builtin_amdgcn_mfma_f32_16x16x32_bf16(ah, bhi[nt], acc[mt][nt], 0, 0, 0);
        acc[mt][nt] = __builtin_amdgcn_mfma_f32_16x16x32_bf16(ah, blo[nt], acc[mt][nt], 0, 0, 0);
        acc[mt][nt] = __builtin_amdgcn_mfma_f32_16x16x32_bf16(al, bhi[nt], acc[mt][nt], 0, 0, 0);
      }
    }
  }

  if (!d1) {
#pragma unroll
    for (int mt = 0; mt < 2; ++mt) {
      const int mb = (wq << 5) + (mt << 4) + (quad << 2);
#pragma unroll
      for (int nt = 0; nt < 4; ++nt) {
        const int nn = (nt << 4) + l15;
        const f4v a = acc[mt][nt];
#pragma unroll
        for (int reg = 0; reg < 4; ++reg) D2[mb + reg][nn] = a[reg];
      }
    }
  }
  __syncthreads();

  if (d1) {
    const unsigned w = diag ? 1u : 2u;
#pragma unroll
    for (int mt = 0; mt < 2; ++mt) {
      const int a0 = (wq << 5) + (mt << 4) + (quad << 2);
#pragma unroll
      for (int nt = 0; nt < 4; ++nt) {
        const int nn = (nt << 4) + l15;
        const int gj = J0 + nn;
        const f4v d1v = acc[mt][nt];
        const f4v d2t = *(const f4v*)&D2[nn][a0];
        f4v vv;
#pragma unroll
        for (int reg = 0; reg < 4; ++reg) {
          const int gi = I0 + a0 + reg;
          float v = 0.f;
          if (gi < NNODE && gj < NNODE) {
            v = xf[(size_t)gi * NNODE + gj];
            if (gi != gj)
              v += 0.5f * (d1v[reg] + d2t[reg] + bias[gj] + bias[gi]);
            const unsigned bin = tokey(v) >> 20;
            atomicAdd(&hist[bin >> 1], w << ((bin & 1) << 4));
          }
          vv[reg] = v;
        }
#pragma unroll
        for (int reg = 0; reg < 4; ++reg) {
          const int gi = I0 + a0 + reg;
          if (gi < NNODE && gj < NNODE) xf[(size_t)gi * NNODE + gj] = vv[reg];
        }
        if (!diag && gj < NNODE && (I0 + a0 + 4 <= NNODE)) {
          *(float4*)(xf + (size_t)gj * NNODE + I0 + a0) = *(float4*)&vv;
        }
      }
    }
  }
  __syncthreads();
  for (int i = tid; i < 2048; i += 256) {
    const unsigned v = hist[i];
    const unsigned lo = v & 0xFFFFu, hi = v >> 16;
    if (lo) atomicAdd(&gh[2 * i], lo);
    if (hi) atomicAdd(&gh[2 * i + 1], hi);
  }
}

// ---------------------------------------------------------------------------
__global__ void tzd(const float* __restrict__ x, unsigned* __restrict__ ghist,
                    unsigned* __restrict__ sprefix, int* __restrict__ sk,
                    int* __restrict__ eqcnt, float* __restrict__ deg,
                    float* __restrict__ denom, unsigned* __restrict__ ccnt2,
                    float* __restrict__ pooled) {
  int t = blockIdx.x * 256 + threadIdx.x;
  if (t < BATCH * 4096) ghist[t] = 0u;
  if (t < BATCH) {
    sprefix[t] = 0u; sk[t] = KSEL; eqcnt[t] = 0;
    float v = x[(size_t)t * NN];
    denom[t] = 0.5f * logf((1.0f + v + EPSF) / (1.0f - v + EPSF));
  }
  if (t < BATCH * TSPLIT) ccnt2[t] = 0u;
  if (t < BATCH * NNODE) deg[t] = 0.f;
  if (t < BATCH * HID) pooled[t] = 0.f;
}

// ---------------------------------------------------------------------------
// thistA: pass A of radix select — bins = bits 19..8 (4096), prefix = top 12.
// Compacts matching keys into this block's PRIVATE segment via an LDS
// counter (no global atomics in the hot loop).
// ---------------------------------------------------------------------------
__global__ void __launch_bounds__(256) thistA(const float* __restrict__ x2,
                                              const unsigned* __restrict__ sprefix,
                                              unsigned* __restrict__ ghist,
                                              unsigned* __restrict__ cand,
                                              unsigned* __restrict__ ccnt2) {
  __shared__ unsigned h[4096];
  __shared__ unsigned lcnt;
  const int b  = blockIdx.y;
  const int sb = blockIdx.x;
  const int tid = threadIdx.x;
  for (int i = tid; i < 4096; i += 256) h[i] = 0u;
  if (tid == 0) lcnt = 0u;
  __syncthreads();

  const unsigned prefix = sprefix[b];
  unsigned* cb = cand + (size_t)b * NN + (size_t)sb * SEG;   // private segment
  const float4* p4 = (const float4*)(x2 + (size_t)b * NN);
  const int i0 = sb * (SEG / 4), i1 = i0 + (SEG / 4);
  for (int i = i0 + tid; i < i1; i += 256) {
    float4 v = p4[i];
    unsigned kk[4] = {tokey(v.x), tokey(v.y), tokey(v.z), tokey(v.w)};
#pragma unroll
    for (int q = 0; q < 4; ++q) {
      const unsigned key = kk[q];
      if ((key & 0xFFF00000u) == prefix) {
        atomicAdd(&h[(key >> 8) & 4095u], 1u);
        const unsigned pos = atomicAdd(&lcnt, 1u);   // LDS atomic: cheap
        cb[pos] = key;
      }
    }
  }
  __syncthreads();
  for (int i = tid; i < 4096; i += 256) {
    unsigned s = h[i];
    if (s) atomicAdd(&ghist[(size_t)b * 4096 + i], s);
  }
  if (tid == 0) ccnt2[b * TSPLIT + sb] = lcnt;       // plain store, no atomic
}

// ---------------------------------------------------------------------------
template<int SH>
__global__ void __launch_bounds__(256) tpick12(unsigned* __restrict__ ghist,
                                               unsigned* __restrict__ sprefix,
                                               int* __restrict__ sk) {
  const int b = blockIdx.x;
  __shared__ unsigned h[4096];
  __shared__ unsigned csum[256];
  unsigned* gh = ghist + (size_t)b * 4096;
  unsigned local = 0;
#pragma unroll
  for (int u = 0; u < 16; ++u) {
    unsigned v = gh[threadIdx.x * 16 + u];
    h[threadIdx.x * 16 + u] = v;
    local += v;
  }
  csum[threadIdx.x] = local;
  __syncthreads();
  if (threadIdx.x == 0) {
    int k = sk[b];
    int bin = 0;
    for (int ch = 255; ch >= 0; --ch) {
      int S = (int)csum[ch];
      if (S >= k) {
        for (int bb = ch * 16 + 15; bb >= ch * 16; --bb) {
          int c = (int)h[bb];
          if (c >= k) { bin = bb; break; }
          k -= c;
        }
        break;
      }
      k -= S;
    }
    sprefix[b] = sprefix[b] | ((unsigned)bin << SH);
    sk[b] = k;
  }
#pragma unroll
  for (int u = 0; u < 16; ++u) gh[threadIdx.x * 16 + u] = 0u;
}

// ---------------------------------------------------------------------------
// thistC: absorbs tpick12<8> (12-bit pick over ghist) AND the final 8-bit
// pass over the 8 per-block candidate segments; emits tau/rrem.
// ---------------------------------------------------------------------------
__global__ void __launch_bounds__(256) thistC(const unsigned* __restrict__ ghist,
                                              const unsigned* __restrict__ cand,
                                              const unsigned* __restrict__ ccnt2,
                                              const unsigned* __restrict__ sprefix,
                                              const int* __restrict__ sk,
                                              unsigned* __restrict__ tau,
                                              int* __restrict__ rrem) {
  __shared__ unsigned h12[4096];
  __shared__ unsigned csum[256];
  __shared__ unsigned h8[8][256];
  __shared__ unsigned spfx;
  __shared__ int skk;
  const int b = blockIdx.x;
  const int tid = threadIdx.x;
  const unsigned* gh = ghist + (size_t)b * 4096;
  unsigned local = 0;
#pragma unroll
  for (int u = 0; u < 16; ++u) {
    unsigned v = gh[tid * 16 + u];
    h12[tid * 16 + u] = v;
    local += v;
  }
  csum[tid] = local;
  for (int i = tid; i < 8 * 256; i += 256) ((unsigned*)h8)[i] = 0u;
  __syncthreads();
  if (tid == 0) {
    int k = sk[b];
    int bin = 0;
    for (int ch = 255; ch >= 0; --ch) {
      int S = (int)csum[ch];
      if (S >= k) {
        for (int bb = ch * 16 + 15; bb >= ch * 16; --bb) {
          int c = (int)h12[bb];
          if (c >= k) { bin = bb; break; }
          k -= c;
        }
        break;
      }
      k -= S;
    }
    spfx = sprefix[b] | ((unsigned)bin << 8);
    skk = k;
  }
  __syncthreads();
  const unsigned prefix = spfx;                 // top 24 bits set
  const int rep = tid & 7;
  for (int sb = 0; sb < TSPLIT; ++sb) {
    const unsigned n = ccnt2[b * TSPLIT + sb];
    const unsigned* cp = cand + (size_t)b * NN + (size_t)sb * SEG;
    for (unsigned i = tid; i < n; i += 256) {
      const unsigned key = cp[i];
      if ((key & 0xFFFFFF00u) == prefix) atomicAdd(&h8[rep][key & 255u], 1u);
    }
  }
  __syncthreads();
  if (tid < 256) {
    const unsigned s = h8[0][tid] + h8[1][tid] + h8[2][tid] + h8[3][tid]
                     + h8[4][tid] + h8[5][tid] + h8[6][tid] + h8[7][tid];
    h8[0][tid] = s;
  }
  __syncthreads();
  if (tid == 0) {
    int k = skk;
    unsigned byte = 0u;
    for (int bin = 255; bin >= 0; --bin) {
      int c = (int)h8[0][bin];
      if (c >= k) { byte = (unsigned)bin; break; }
      k -= c;
    }
    tau[b] = prefix | byte;
    rrem[b] = k;
  }
}

// ---------------------------------------------------------------------------
// eqdinv: fused tie-fix + diag-fill + dinv, one block per sample.
// ---------------------------------------------------------------------------
__global__ void __launch_bounds__(256) eqdinv(
    float* __restrict__ A, const float* __restrict__ x2,
    float* __restrict__ deg, float* __restrict__ dinv,
    const int* __restrict__ eqcnt, const int* __restrict__ eqidx,
    const int* __restrict__ rrem) {
  const int b = blockIdx.x;
  int cnt = eqcnt[b]; if (cnt > EQCAP) cnt = EQCAP;
  const int r = rrem[b];
  for (int t = threadIdx.x; t < cnt; t += 256) {
    int idx = eqidx[b * EQCAP + t];
    int rank = 0;
    for (int u = 0; u < cnt; ++u) rank += (eqidx[b * EQCAP + u] < idx) ? 1 : 0;
    if (rank < r) {
      float v = x2[(size_t)b * NN + idx];
      A[(size_t)b * NN + idx] = v;
      atomicAdd(&deg[b * NNODE + idx % NNODE], v);
    }
  }
  __syncthreads();
  for (int j = threadIdx.x; j < NNODE; j += 256) {
    float d = deg[b * NNODE + j];
    size_t o = (size_t)b * NN + (size_t)j * NNODE + j;
    if (A[o] == 0.f) { A[o] = 1.0f; d += 1.0f; }
    dinv[b * NNODE + j] = (d == 0.f) ? 0.f : 1.0f / sqrtf(d);
  }
}

// head: pooled sums (from AT2-POOL) -> mean -> relu -> fc
__global__ void head_k(const float* __restrict__ pooled, const float* __restrict__ fc_w,
                       const float* __restrict__ fc_b, float* __restrict__ out) {
  int b = blockIdx.x;
  int f = threadIdx.x;
  float pv = fmaxf(pooled[(size_t)b * HID + f] / (float)NNODE, 0.f);
  __shared__ float r0[128], r1[128];
  r0[f] = pv * fc_w[f * 2 + 0];
  r1[f] = pv * fc_w[f * 2 + 1];
  __syncthreads();
  for (int sft = 64; sft > 0; sft >>= 1) {
    if (f < sft) { r0[f] += r0[f + sft]; r1[f] += r1[f + sft]; }
    __syncthreads();
  }
  if (f == 0) {
    out[b * 2 + 0] = r0[0] + fc_b[0];
    out[b * 2 + 1] = r1[0] + fc_b[1];
  }
}

// ---------------------------------------------------------------------------
extern "C" void kernel_launch(void* const* d_in, const int* in_sizes, int n_in,
                              void* d_out, int out_size, void* d_ws, size_t ws_size,
                              hipStream_t stream) {
  const float* x      = (const float*)d_in[0];
  const float* enc1_w = (const float*)d_in[2];
  const float* enc1_b = (const float*)d_in[3];
  const float* enc2_w = (const float*)d_in[4];
  const float* enc2_b = (const float*)d_in[5];
  const float* dec2_w = (const float*)d_in[6];
  const float* dec2_b = (const float*)d_in[7];
  const float* dec1_w = (const float*)d_in[8];
  const float* dec1_b = (const float*)d_in[9];
  const float* gcn1_w = (const float*)d_in[10];
  const float* gcn1_b = (const float*)d_in[11];
  const float* gcn2_w = (const float*)d_in[12];
  const float* gcn2_b = (const float*)d_in[13];
  const float* fc_w   = (const float*)d_in[14];
  const float* fc_b   = (const float*)d_in[15];
  float* out = (float*)d_out;
  (void)in_sizes; (void)n_in; (void)out_size; (void)ws_size;

  float* ws = (float*)d_ws;
  size_t off = 0;
  auto take = [&](size_t n) { float* p = ws + off; off += (n + 63) & ~(size_t)63; return p; };
  float* xf   = take((size_t)BATCH * NN);          // xf -> x2 (in place)
  float* dl   = take((size_t)BATCH * NN);          // cand keys (radix), then A (sparsified)
  float* o1   = take((size_t)BATCH * HID * NNODE); // out1 -> out2b; later xwfrag alias
  float* o2   = take((size_t)BATCH * HID * HID);
  float* hbuf = take((size_t)BATCH * NNODE * HID); // h (GCN1 out)
  float* denom = take(BATCH);
  float* dinv  = take((size_t)BATCH * NNODE);
  float* deg   = take((size_t)BATCH * NNODE);
  float* pooled = take((size_t)BATCH * HID);
  unsigned* tau = (unsigned*)take(BATCH);
  int* rrem  = (int*)take(BATCH);
  int* eqcnt = (int*)take(BATCH);
  int* eqidx = (int*)take((size_t)BATCH * EQCAP);
  unsigned* ghist   = (unsigned*)take((size_t)BATCH * 4096);   // 12-bit bins
  unsigned* sprefix = (unsigned*)take(BATCH);
  int*      sk      = (int*)take(BATCH);
  unsigned* ccnt2   = (unsigned*)take((size_t)BATCH * TSPLIT); // per-(b,sb) counts
  short* w1frag = (short*)take((size_t)FRAGS + 64);          // gcn1_w, 2 planes K448
  short* w2frag = (short*)take((size_t)4 * 4096 + 64);       // gcn2_w, 2 planes K128
  short* e1frag = (short*)take((size_t)FRAGS + 64);          // enc1_w
  short* e2frag = (short*)take((size_t)FRAGS + 64);          // enc2_w
  short* dfrag  = (short*)take((size_t)PLA + 64);            // dec1_w (2*PLA shorts)
  short* xwfrag = (short*)o1;          // aliases dead o1 (post-g4mf)
  unsigned* cand = (unsigned*)dl;      // candidate keys, dead before the MASK kernel
  const long sXW = 2L * FRAGS;

  tzd<<<2048, 256, 0, stream>>>(x, ghist, sprefix, sk, eqcnt, deg, denom, ccnt2, pooled);
  bsplit5<<<dim3(224, 5), 256, 0, stream>>>(gcn1_w, gcn2_w, enc1_w, enc2_w, dec1_w,
                                            w1frag, w2frag, e1frag, e2frag, dfrag);

  // G1 (+fused xf): reads raw x, computes/stores xf, o1 = (relu(xf@enc1_w+b))^T
  mfgemm<false, false, true, true, false, true, true, false, false, false><<<dim3(7, BATCH), 256, 0, stream>>>(
      x, NN, NNODE, e1frag, 0, KC400, enc1_b, nullptr,
      o1, (long)HID * NNODE, NNODE, nullptr, 0, 0, denom, xf,
      nullptr, nullptr, nullptr, nullptr, nullptr, nullptr, nullptr, NNODE, NNODE);
  // G2: o2 = relu(o1 @ enc2_w + b)
  mfgemm<false, false, true, true, false, false, false, false, false, false><<<dim3(2, BATCH), 256, 0, stream>>>(
      o1, (long)HID * NNODE, NNODE, e2frag, 0, KC400, enc2_b, nullptr,
      o2, (long)HID * HID, HID, nullptr, 0, 0, nullptr, nullptr,
      nullptr, nullptr, nullptr, nullptr, nullptr, nullptr, nullptr, HID, NNODE);
  // G3: out2b = relu(o2 @ dec2_w + b + o1), in-place (fp32)
  gemm64<false, true, true, true, false><<<dim3(7, 2, BATCH), 256, 0, stream>>>(
      o2, (long)HID * HID, HID, dec2_w, 0, NNODE, dec2_b,
      o1, (long)HID * NNODE, o1, (long)HID * NNODE, NNODE, HID, NNODE, HID);

  // fused delta + symmetrize + x2 + pass-0 12-bit histogram (packed LDS)
  g4mf<<<dim3(NT * (NT + 1) / 2, BATCH), 256, 0, stream>>>(o1, dfrag, dec1_b, xf, ghist);

  // radix select: 12 + 12 + 8 bits; final two picks fused into thistC
  tpick12<20><<<BATCH, 256, 0, stream>>>(ghist, sprefix, sk);
  thistA<<<dim3(TSPLIT, BATCH), 256, 0, stream>>>(xf, sprefix, ghist, cand, ccnt2);
  thistC<<<BATCH, 256, 0, stream>>>(ghist, cand, ccnt2, sprefix, sk, tau, rrem);

  // GCN1-frag (UNscaled xw = x2@w1) + fused build_kc (A/deg/ties) — MASK=true.
  mfgemm<false, true, false, false, false, false, false, true, false, false><<<dim3(7, BATCH), 256, 0, stream>>>(
      xf, NN, NNODE, w1frag, 0, KC400, nullptr, nullptr,
      nullptr, 0, 128, xwfrag, sXW, KC400, nullptr, nullptr,
      tau, dl, deg, eqcnt, eqidx, nullptr, nullptr, NNODE, NNODE);
  // tie-fix + diag-fill + dinv
  eqdinv<<<BATCH, 256, 0, stream>>>(dl, xf, deg, dinv, eqcnt, eqidx, rrem);

  // AT-gather 1: h = relu(dinv[j] * sum_i (A[i,j]*dinv[i]) * xw[i,f] + b1)
  mfgemm<true, false, true, true, true, false, false, false, true, false><<<dim3(7, BATCH), 256, 0, stream>>>(
      dl, NN, NNODE, xwfrag, sXW, KC400, gcn1_b, dinv,
      hbuf, (long)NNODE * HID, HID, nullptr, 0, 0, nullptr, nullptr,
      nullptr, nullptr, nullptr, nullptr, nullptr, dinv, nullptr, NNODE, NNODE);
  // GCN2-frag (UNscaled h@w2)
  mfgemm<false, true, false, false, false, false, false, false, false, false><<<dim3(7, BATCH), 256, 0, stream>>>(
      hbuf, (long)NNODE * HID, HID, w2frag, 0, 4, nullptr, nullptr,
      nullptr, 0, 128, xwfrag, sXW, KC400, nullptr, nullptr,
      nullptr, nullptr, nullptr, nullptr, nullptr, nullptr, nullptr, NNODE, HID);
  // AT-gather 2 + POOL: pooled[f] += sum_j h2[j][f] (h2 never materialized)
  mfgemm<true, false, true, false, true, false, false, false, true, true><<<dim3(7, BATCH), 256, 0, stream>>>(
      dl, NN, NNODE, xwfrag, sXW, KC400, gcn2_b, dinv,
      nullptr, 0, HID, nullptr, 0, 0, nullptr, nullptr,
      nullptr, nullptr, nullptr, nullptr, nullptr, dinv, pooled, NNODE, NNODE);

  head_k<<<BATCH, HID, 0, stream>>>(pooled, fc_w, fc_b, out);
}